// Round 2
// baseline (1684.656 us; speedup 1.0000x reference)
//
#include <hip/hip_runtime.h>
#include <math.h>

#define H_HEADS 8
#define C_DIM 32
#define HC_DIM 256
#define E_DIM 32

static __device__ __forceinline__ const float4& ldf4(const float* p) {
    return *reinterpret_cast<const float4*>(p);
}

// ---------------- CSR build ----------------
__global__ __launch_bounds__(256) void count_kernel(const int* __restrict__ dst, int E,
                                                    int* __restrict__ cnt) {
    int e = blockIdx.x * 256 + threadIdx.x;
    if (e < E) atomicAdd(&cnt[dst[e]], 1);
}

__global__ __launch_bounds__(1024) void scan_kernel(int* __restrict__ cnt,
                                                    int* __restrict__ rowptr, int n) {
    __shared__ int sm[1024];
    __shared__ int carry;
    if (threadIdx.x == 0) carry = 0;
    __syncthreads();
    for (int base = 0; base < n; base += 1024) {
        int i = base + (int)threadIdx.x;
        int val = (i < n) ? cnt[i] : 0;
        sm[threadIdx.x] = val;
        __syncthreads();
        for (int off = 1; off < 1024; off <<= 1) {
            int t = (threadIdx.x >= (unsigned)off) ? sm[threadIdx.x - off] : 0;
            __syncthreads();
            sm[threadIdx.x] += t;
            __syncthreads();
        }
        int incl = sm[threadIdx.x];
        int excl = carry + incl - val;
        if (i < n) { rowptr[i] = excl; cnt[i] = excl; }
        __syncthreads();
        if (threadIdx.x == 1023) carry += sm[1023];
        __syncthreads();
    }
    if (threadIdx.x == 0) rowptr[n] = carry;
}

// store (src, e) pairs so the attention loop has one indirection, not two
__global__ __launch_bounds__(256) void scatter_kernel(const int* __restrict__ src,
                                                      const int* __restrict__ dst, int E,
                                                      int* __restrict__ cursor,
                                                      int2* __restrict__ el2) {
    int e = blockIdx.x * 256 + threadIdx.x;
    if (e < E) {
        int p = atomicAdd(&cursor[dst[e]], 1);
        el2[p] = make_int2(src[e], e);
    }
}

// ---------------- f32 GEMM 128x128 tile, 8x8 per thread ----------------
// Y[M,N] = A[M,K] @ W[K,N] + bias[N]; requires N multiple of 128 per grid.y tile.
__global__ __launch_bounds__(256) void gemm128(const float* __restrict__ A,
                                               const float* __restrict__ W,
                                               const float* __restrict__ bias,
                                               float* __restrict__ Y,
                                               int M, int N, int K) {
    __shared__ float As[8][136];
    __shared__ float Ws[8][136];
    const int tid = threadIdx.x;
    const int m0 = blockIdx.x * 128, n0 = blockIdx.y * 128;
    const int ar = tid >> 1, ac = (tid & 1) << 2;   // A: row 0..127, k 0/4
    const int wr = tid >> 5, wc = (tid & 31) << 2;  // W: k-row 0..7, col 0..124
    const int ty = tid >> 4, tx = tid & 15;
    float acc[8][8] = {{0.f}};
    for (int k0 = 0; k0 < K; k0 += 8) {
        float4 a = {0.f, 0.f, 0.f, 0.f};
        if (m0 + ar < M) a = ldf4(A + (size_t)(m0 + ar) * K + k0 + ac);
        As[ac + 0][ar] = a.x; As[ac + 1][ar] = a.y;
        As[ac + 2][ar] = a.z; As[ac + 3][ar] = a.w;
        float4 w = ldf4(W + (size_t)(k0 + wr) * N + n0 + wc);
        *reinterpret_cast<float4*>(&Ws[wr][wc]) = w;
        __syncthreads();
#pragma unroll
        for (int kk = 0; kk < 8; ++kk) {
            float4 a0 = *reinterpret_cast<const float4*>(&As[kk][ty * 8]);
            float4 a1 = *reinterpret_cast<const float4*>(&As[kk][ty * 8 + 4]);
            float4 b0 = *reinterpret_cast<const float4*>(&Ws[kk][tx * 8]);
            float4 b1 = *reinterpret_cast<const float4*>(&Ws[kk][tx * 8 + 4]);
            float av[8] = {a0.x, a0.y, a0.z, a0.w, a1.x, a1.y, a1.z, a1.w};
            float bv[8] = {b0.x, b0.y, b0.z, b0.w, b1.x, b1.y, b1.z, b1.w};
#pragma unroll
            for (int i = 0; i < 8; ++i)
#pragma unroll
                for (int j = 0; j < 8; ++j)
                    acc[i][j] = fmaf(av[i], bv[j], acc[i][j]);
        }
        __syncthreads();
    }
    float4 bb0 = ldf4(bias + n0 + tx * 8);
    float4 bb1 = ldf4(bias + n0 + tx * 8 + 4);
#pragma unroll
    for (int i = 0; i < 8; ++i) {
        int m = m0 + ty * 8 + i;
        if (m < M) {
            float4 o0, o1;
            o0.x = acc[i][0] + bb0.x; o0.y = acc[i][1] + bb0.y;
            o0.z = acc[i][2] + bb0.z; o0.w = acc[i][3] + bb0.w;
            o1.x = acc[i][4] + bb1.x; o1.y = acc[i][5] + bb1.y;
            o1.z = acc[i][6] + bb1.z; o1.w = acc[i][7] + bb1.w;
            float* yp = Y + (size_t)m * N + n0 + tx * 8;
            *reinterpret_cast<float4*>(yp) = o0;
            *reinterpret_cast<float4*>(yp + 4) = o1;
        }
    }
}

// ---------------- small-N GEMM (N=32): old 64x64 tile ----------------
__global__ __launch_bounds__(256) void gemm_bias(const float* __restrict__ A,
                                                 const float* __restrict__ W,
                                                 const float* __restrict__ bias,
                                                 float* __restrict__ Y,
                                                 int M, int N, int K) {
    __shared__ float As[16][68];
    __shared__ float Ws[16][68];
    const int tid = threadIdx.x;
    const int tx = tid & 15, ty = tid >> 4;
    const int m0 = blockIdx.x * 64, n0 = blockIdx.y * 64;
    const int lm = tid >> 2;
    const int lk = (tid & 3) << 2;
    const int wk = tid >> 4;
    const int wn = (tid & 15) << 2;
    float acc[4][4] = {{0.f}};
    for (int k0 = 0; k0 < K; k0 += 16) {
        float4 a = {0.f, 0.f, 0.f, 0.f};
        if (m0 + lm < M) a = ldf4(A + (size_t)(m0 + lm) * K + k0 + lk);
        As[lk + 0][lm] = a.x; As[lk + 1][lm] = a.y;
        As[lk + 2][lm] = a.z; As[lk + 3][lm] = a.w;
        float4 w = {0.f, 0.f, 0.f, 0.f};
        if (n0 + wn < N) w = ldf4(W + (size_t)(k0 + wk) * N + n0 + wn);
        *reinterpret_cast<float4*>(&Ws[wk][wn]) = w;
        __syncthreads();
#pragma unroll
        for (int kk = 0; kk < 16; ++kk) {
            float4 av = *reinterpret_cast<const float4*>(&As[kk][ty << 2]);
            float4 bv = *reinterpret_cast<const float4*>(&Ws[kk][tx << 2]);
            float aa[4] = {av.x, av.y, av.z, av.w};
            float bb[4] = {bv.x, bv.y, bv.z, bv.w};
#pragma unroll
            for (int i = 0; i < 4; ++i)
#pragma unroll
                for (int j = 0; j < 4; ++j)
                    acc[i][j] = fmaf(aa[i], bb[j], acc[i][j]);
        }
        __syncthreads();
    }
    if (n0 + (tx << 2) < N) {
        float4 bb = ldf4(bias + n0 + (tx << 2));
#pragma unroll
        for (int i = 0; i < 4; ++i) {
            int m = m0 + (ty << 2) + i;
            if (m < M) {
                float4 o;
                o.x = acc[i][0] + bb.x; o.y = acc[i][1] + bb.y;
                o.z = acc[i][2] + bb.z; o.w = acc[i][3] + bb.w;
                *reinterpret_cast<float4*>(Y + (size_t)m * N + n0 + (tx << 2)) = o;
            }
        }
    }
}

// ---------------- conv1 attention: one wave per dst node ----------------
// lane owns hc = 4*lane..4*lane+3 ; head h = lane>>3 ; edge-dim slice d0 = (lane&7)*4
// P[h,d] = sum_c q[h,c]*we[d,h*32+c]  (node prologue)
// logit  = (q.k + sum_d ea[d]*P[h,d]) / sqrt(C)
// msg    = (sum_e w_e*v + (sum_e w_e*ea) @ we) / denom
__global__ __launch_bounds__(256) void attn1_kernel(
    const float* __restrict__ q, const float* __restrict__ k,
    const float* __restrict__ v, const float* __restrict__ skip,
    const float* __restrict__ ea, const float* __restrict__ we,
    const int2* __restrict__ el2, const int* __restrict__ rowptr,
    const float* __restrict__ gamma, const float* __restrict__ beta,
    float* __restrict__ hout, int nN) {
    const int wid = threadIdx.x >> 6, lane = threadIdx.x & 63;
    const int node = blockIdx.x * 4 + wid;
    if (node >= nN) return;
    const int hc0 = lane << 2;
    const int h = lane >> 3;
    const int d0 = (lane & 7) << 2;

    const float4 qv = ldf4(q + (size_t)node * HC_DIM + hc0);
    // prologue: P4[dd] = P[h, d0+dd]
    float P4[4] = {0.f, 0.f, 0.f, 0.f};
#pragma unroll
    for (int j = 0; j < 8; ++j) {
        float qx = __shfl(qv.x, j, 8), qy = __shfl(qv.y, j, 8);
        float qz = __shfl(qv.z, j, 8), qw = __shfl(qv.w, j, 8);
        const float* wrow = we + h * 32 + j * 4;
#pragma unroll
        for (int dd = 0; dd < 4; ++dd) {
            float4 wv = ldf4(wrow + (size_t)(d0 + dd) * HC_DIM);
            P4[dd] = fmaf(qx, wv.x, fmaf(qy, wv.y, fmaf(qz, wv.z, fmaf(qw, wv.w, P4[dd]))));
        }
    }

    float m = -INFINITY, denom = 0.f;
    float ax = 0.f, ay = 0.f, az = 0.f, aw = 0.f;
    float A4[4] = {0.f, 0.f, 0.f, 0.f};
    const int e0 = rowptr[node], e1 = rowptr[node + 1];
    for (int base = e0; base < e1; base += 4) {
        int2 ee[4]; float4 ku[4], vu[4], au[4];
#pragma unroll
        for (int u = 0; u < 4; ++u) {
            int idx = (base + u < e1) ? base + u : e1 - 1;
            ee[u] = el2[idx];
        }
#pragma unroll
        for (int u = 0; u < 4; ++u) {
            ku[u] = ldf4(k + (size_t)ee[u].x * HC_DIM + hc0);
            vu[u] = ldf4(v + (size_t)ee[u].x * HC_DIM + hc0);
            au[u] = ldf4(ea + (size_t)ee[u].y * E_DIM + d0);
        }
#pragma unroll
        for (int u = 0; u < 4; ++u) {
            if (base + u < e1) {
                float lp = qv.x * ku[u].x + qv.y * ku[u].y + qv.z * ku[u].z + qv.w * ku[u].w
                         + au[u].x * P4[0] + au[u].y * P4[1] + au[u].z * P4[2] + au[u].w * P4[3];
                lp += __shfl_xor(lp, 1); lp += __shfl_xor(lp, 2); lp += __shfl_xor(lp, 4);
                const float l = lp * 0.17677669529663687f;  // 1/sqrt(32)
                const float mn = fmaxf(m, l);
                const float sc = __expf(m - mn);
                const float w = __expf(l - mn);
                denom = denom * sc + w;
                ax = ax * sc + w * vu[u].x;
                ay = ay * sc + w * vu[u].y;
                az = az * sc + w * vu[u].z;
                aw = aw * sc + w * vu[u].w;
                A4[0] = A4[0] * sc + w * au[u].x;
                A4[1] = A4[1] * sc + w * au[u].y;
                A4[2] = A4[2] * sc + w * au[u].z;
                A4[3] = A4[3] * sc + w * au[u].w;
                m = mn;
            }
        }
    }
    // epilogue: msg_e part = A[h,:] @ we[:, hc0..hc0+3]
    float mx = 0.f, my = 0.f, mz = 0.f, mw = 0.f;
#pragma unroll
    for (int j = 0; j < 8; ++j) {
        float a0 = __shfl(A4[0], j, 8), a1 = __shfl(A4[1], j, 8);
        float a2 = __shfl(A4[2], j, 8), a3 = __shfl(A4[3], j, 8);
        const float* wrow = we + (size_t)(j * 4) * HC_DIM + hc0;
        float4 w0 = ldf4(wrow);
        float4 w1 = ldf4(wrow + HC_DIM);
        float4 w2 = ldf4(wrow + 2 * HC_DIM);
        float4 w3 = ldf4(wrow + 3 * HC_DIM);
        mx += a0 * w0.x + a1 * w1.x + a2 * w2.x + a3 * w3.x;
        my += a0 * w0.y + a1 * w1.y + a2 * w2.y + a3 * w3.y;
        mz += a0 * w0.z + a1 * w1.z + a2 * w2.z + a3 * w3.z;
        mw += a0 * w0.w + a1 * w1.w + a2 * w2.w + a3 * w3.w;
    }
    const float inv = 1.f / (denom + 1e-16f);
    const float4 sk = ldf4(skip + (size_t)node * HC_DIM + hc0);
    float ox = fmaxf((ax + mx) * inv + sk.x, 0.f);
    float oy = fmaxf((ay + my) * inv + sk.y, 0.f);
    float oz = fmaxf((az + mz) * inv + sk.z, 0.f);
    float ow = fmaxf((aw + mw) * inv + sk.w, 0.f);
    float s1 = ox + oy + oz + ow;
    float s2 = ox * ox + oy * oy + oz * oz + ow * ow;
#pragma unroll
    for (int msk = 1; msk < 64; msk <<= 1) {
        s1 += __shfl_xor(s1, msk);
        s2 += __shfl_xor(s2, msk);
    }
    const float mu = s1 * (1.f / 256.f);
    const float var = s2 * (1.f / 256.f) - mu * mu;
    const float rstd = rsqrtf(var + 1e-5f);
    const float4 gv = ldf4(gamma + hc0);
    const float4 bv = ldf4(beta + hc0);
    float4 o;
    o.x = (ox - mu) * rstd * gv.x + bv.x;
    o.y = (oy - mu) * rstd * gv.y + bv.y;
    o.z = (oz - mu) * rstd * gv.z + bv.z;
    o.w = (ow - mu) * rstd * gv.w + bv.w;
    *reinterpret_cast<float4*>(hout + (size_t)node * HC_DIM + hc0) = o;
}

// ---------------- conv2 attention + head-mean + skip + relu + final linear ----------------
__global__ __launch_bounds__(256) void attn2_kernel(
    const float* __restrict__ q, const float* __restrict__ k,
    const float* __restrict__ v, const float* __restrict__ skip2,
    const float* __restrict__ ea, const float* __restrict__ we,
    const int2* __restrict__ el2, const int* __restrict__ rowptr,
    const float* __restrict__ wc, const float* __restrict__ bc,
    float* __restrict__ out, int nN) {
    const int wid = threadIdx.x >> 6, lane = threadIdx.x & 63;
    const int node = blockIdx.x * 4 + wid;
    if (node >= nN) return;
    const int hc0 = lane << 2;
    const int h = lane >> 3;
    const int d0 = (lane & 7) << 2;

    const float4 qv = ldf4(q + (size_t)node * HC_DIM + hc0);
    float P4[4] = {0.f, 0.f, 0.f, 0.f};
#pragma unroll
    for (int j = 0; j < 8; ++j) {
        float qx = __shfl(qv.x, j, 8), qy = __shfl(qv.y, j, 8);
        float qz = __shfl(qv.z, j, 8), qw = __shfl(qv.w, j, 8);
        const float* wrow = we + h * 32 + j * 4;
#pragma unroll
        for (int dd = 0; dd < 4; ++dd) {
            float4 wv = ldf4(wrow + (size_t)(d0 + dd) * HC_DIM);
            P4[dd] = fmaf(qx, wv.x, fmaf(qy, wv.y, fmaf(qz, wv.z, fmaf(qw, wv.w, P4[dd]))));
        }
    }

    float m = -INFINITY, denom = 0.f;
    float ax = 0.f, ay = 0.f, az = 0.f, aw = 0.f;
    float A4[4] = {0.f, 0.f, 0.f, 0.f};
    const int e0 = rowptr[node], e1 = rowptr[node + 1];
    for (int base = e0; base < e1; base += 4) {
        int2 ee[4]; float4 ku[4], vu[4], au[4];
#pragma unroll
        for (int u = 0; u < 4; ++u) {
            int idx = (base + u < e1) ? base + u : e1 - 1;
            ee[u] = el2[idx];
        }
#pragma unroll
        for (int u = 0; u < 4; ++u) {
            ku[u] = ldf4(k + (size_t)ee[u].x * HC_DIM + hc0);
            vu[u] = ldf4(v + (size_t)ee[u].x * HC_DIM + hc0);
            au[u] = ldf4(ea + (size_t)ee[u].y * E_DIM + d0);
        }
#pragma unroll
        for (int u = 0; u < 4; ++u) {
            if (base + u < e1) {
                float lp = qv.x * ku[u].x + qv.y * ku[u].y + qv.z * ku[u].z + qv.w * ku[u].w
                         + au[u].x * P4[0] + au[u].y * P4[1] + au[u].z * P4[2] + au[u].w * P4[3];
                lp += __shfl_xor(lp, 1); lp += __shfl_xor(lp, 2); lp += __shfl_xor(lp, 4);
                const float l = lp * 0.17677669529663687f;
                const float mn = fmaxf(m, l);
                const float sc = __expf(m - mn);
                const float w = __expf(l - mn);
                denom = denom * sc + w;
                ax = ax * sc + w * vu[u].x;
                ay = ay * sc + w * vu[u].y;
                az = az * sc + w * vu[u].z;
                aw = aw * sc + w * vu[u].w;
                A4[0] = A4[0] * sc + w * au[u].x;
                A4[1] = A4[1] * sc + w * au[u].y;
                A4[2] = A4[2] * sc + w * au[u].z;
                A4[3] = A4[3] * sc + w * au[u].w;
                m = mn;
            }
        }
    }
    float mx = 0.f, my = 0.f, mz = 0.f, mw = 0.f;
#pragma unroll
    for (int j = 0; j < 8; ++j) {
        float a0 = __shfl(A4[0], j, 8), a1 = __shfl(A4[1], j, 8);
        float a2 = __shfl(A4[2], j, 8), a3 = __shfl(A4[3], j, 8);
        const float* wrow = we + (size_t)(j * 4) * HC_DIM + hc0;
        float4 w0 = ldf4(wrow);
        float4 w1 = ldf4(wrow + HC_DIM);
        float4 w2 = ldf4(wrow + 2 * HC_DIM);
        float4 w3 = ldf4(wrow + 3 * HC_DIM);
        mx += a0 * w0.x + a1 * w1.x + a2 * w2.x + a3 * w3.x;
        my += a0 * w0.y + a1 * w1.y + a2 * w2.y + a3 * w3.y;
        mz += a0 * w0.z + a1 * w1.z + a2 * w2.z + a3 * w3.z;
        mw += a0 * w0.w + a1 * w1.w + a2 * w2.w + a3 * w3.w;
    }
    const float inv = 1.f / (denom + 1e-16f);
    float ox = (ax + mx) * inv, oy = (ay + my) * inv;
    float oz = (az + mz) * inv, ow = (aw + mw) * inv;
    // mean over heads: sum lanes with equal (lane&7)
#pragma unroll
    for (int msk = 8; msk < 64; msk <<= 1) {
        ox += __shfl_xor(ox, msk);
        oy += __shfl_xor(oy, msk);
        oz += __shfl_xor(oz, msk);
        ow += __shfl_xor(ow, msk);
    }
    const int c0 = (lane & 7) << 2;
    const float4 sk = ldf4(skip2 + (size_t)node * C_DIM + c0);
    const float yx = fmaxf(ox * 0.125f + sk.x, 0.f);
    const float yy = fmaxf(oy * 0.125f + sk.y, 0.f);
    const float yz = fmaxf(oz * 0.125f + sk.z, 0.f);
    const float yw = fmaxf(ow * 0.125f + sk.w, 0.f);
    float p0 = yx * wc[(c0 + 0) * 2 + 0] + yy * wc[(c0 + 1) * 2 + 0] +
               yz * wc[(c0 + 2) * 2 + 0] + yw * wc[(c0 + 3) * 2 + 0];
    float p1 = yx * wc[(c0 + 0) * 2 + 1] + yy * wc[(c0 + 1) * 2 + 1] +
               yz * wc[(c0 + 2) * 2 + 1] + yw * wc[(c0 + 3) * 2 + 1];
#pragma unroll
    for (int msk = 1; msk < 8; msk <<= 1) {
        p0 += __shfl_xor(p0, msk);
        p1 += __shfl_xor(p1, msk);
    }
    if (lane == 0) {
        out[(size_t)node * 2 + 0] = p0 + bc[0];
        out[(size_t)node * 2 + 1] = p1 + bc[1];
    }
}

extern "C" void kernel_launch(void* const* d_in, const int* in_sizes, int n_in,
                              void* d_out, int out_size, void* d_ws, size_t ws_size,
                              hipStream_t stream) {
    const float* x        = (const float*)d_in[0];
    const int*   eidx     = (const int*)d_in[1];
    const float* eattr    = (const float*)d_in[2];
    const float* wq1      = (const float*)d_in[3];
    const float* bq1      = (const float*)d_in[4];
    const float* wk1      = (const float*)d_in[5];
    const float* bk1      = (const float*)d_in[6];
    const float* wv1      = (const float*)d_in[7];
    const float* bv1      = (const float*)d_in[8];
    const float* we1      = (const float*)d_in[9];
    const float* wskip1   = (const float*)d_in[10];
    const float* bskip1   = (const float*)d_in[11];
    const float* g1       = (const float*)d_in[12];
    const float* b1       = (const float*)d_in[13];
    const float* wq2      = (const float*)d_in[14];
    const float* bq2      = (const float*)d_in[15];
    const float* wk2      = (const float*)d_in[16];
    const float* bk2      = (const float*)d_in[17];
    const float* wv2      = (const float*)d_in[18];
    const float* bv2      = (const float*)d_in[19];
    const float* we2      = (const float*)d_in[20];
    const float* wskip2   = (const float*)d_in[21];
    const float* bskip2   = (const float*)d_in[22];
    const float* wc       = (const float*)d_in[23];
    const float* bc       = (const float*)d_in[24];

    const int N = in_sizes[0] / 128;
    const int E = in_sizes[2] / 32;
    const int* src = eidx;
    const int* dst = eidx + E;
    float* out = (float*)d_out;

    char* ws = (char*)d_ws;
    const size_t fbytes = (size_t)N * HC_DIM * sizeof(float);
    float* qb = (float*)(ws + 0 * fbytes);
    float* kb = (float*)(ws + 1 * fbytes);
    float* vb = (float*)(ws + 2 * fbytes);
    float* sb = (float*)(ws + 3 * fbytes);  // skip1 [N,256] / skip2 [N,32]
    float* hb = (float*)(ws + 4 * fbytes);
    int* rowptr = (int*)(ws + 5 * fbytes);
    int* cursor = rowptr + (N + 1);
    int2* el2   = (int2*)(cursor + N + 1);  // +1 keeps el2 8B-aligned

    // CSR build
    hipMemsetAsync(cursor, 0, (size_t)N * sizeof(int), stream);
    count_kernel<<<dim3((E + 255) / 256), dim3(256), 0, stream>>>(dst, E, cursor);
    scan_kernel<<<dim3(1), dim3(1024), 0, stream>>>(cursor, rowptr, N);
    scatter_kernel<<<dim3((E + 255) / 256), dim3(256), 0, stream>>>(src, dst, E, cursor, el2);

    // conv1 projections (K=128, N=256)
    dim3 g1g((N + 127) / 128, 2);
    gemm128<<<g1g, dim3(256), 0, stream>>>(x, wq1, bq1, qb, N, 256, 128);
    gemm128<<<g1g, dim3(256), 0, stream>>>(x, wk1, bk1, kb, N, 256, 128);
    gemm128<<<g1g, dim3(256), 0, stream>>>(x, wv1, bv1, vb, N, 256, 128);
    gemm128<<<g1g, dim3(256), 0, stream>>>(x, wskip1, bskip1, sb, N, 256, 128);

    attn1_kernel<<<dim3((N + 3) / 4), dim3(256), 0, stream>>>(
        qb, kb, vb, sb, eattr, we1, el2, rowptr, g1, b1, hb, N);

    // conv2 projections (K=256)
    gemm128<<<g1g, dim3(256), 0, stream>>>(hb, wq2, bq2, qb, N, 256, 256);
    gemm128<<<g1g, dim3(256), 0, stream>>>(hb, wk2, bk2, kb, N, 256, 256);
    gemm128<<<g1g, dim3(256), 0, stream>>>(hb, wv2, bv2, vb, N, 256, 256);
    gemm_bias<<<dim3((N + 63) / 64, 1), dim3(256), 0, stream>>>(hb, wskip2, bskip2, sb, N, 32, 256);

    attn2_kernel<<<dim3((N + 3) / 4), dim3(256), 0, stream>>>(
        qb, kb, vb, sb, eattr, we2, el2, rowptr, wc, bc, out, N);
}

// Round 3
// 1619.324 us; speedup vs baseline: 1.0403x; 1.0403x over previous
//
#include <hip/hip_runtime.h>
#include <math.h>

#define H_HEADS 8
#define C_DIM 32
#define HC_DIM 256
#define E_DIM 32

static __device__ __forceinline__ const float4& ldf4(const float* p) {
    return *reinterpret_cast<const float4*>(p);
}

// ---------------- CSR build ----------------
__global__ __launch_bounds__(256) void count_kernel(const int* __restrict__ dst, int E,
                                                    int* __restrict__ cnt) {
    int e = blockIdx.x * 256 + threadIdx.x;
    if (e < E) atomicAdd(&cnt[dst[e]], 1);
}

__global__ __launch_bounds__(1024) void scan_kernel(int* __restrict__ cnt,
                                                    int* __restrict__ rowptr, int n) {
    __shared__ int sm[1024];
    __shared__ int carry;
    if (threadIdx.x == 0) carry = 0;
    __syncthreads();
    for (int base = 0; base < n; base += 1024) {
        int i = base + (int)threadIdx.x;
        int val = (i < n) ? cnt[i] : 0;
        sm[threadIdx.x] = val;
        __syncthreads();
        for (int off = 1; off < 1024; off <<= 1) {
            int t = (threadIdx.x >= (unsigned)off) ? sm[threadIdx.x - off] : 0;
            __syncthreads();
            sm[threadIdx.x] += t;
            __syncthreads();
        }
        int incl = sm[threadIdx.x];
        int excl = carry + incl - val;
        if (i < n) { rowptr[i] = excl; cnt[i] = excl; }
        __syncthreads();
        if (threadIdx.x == 1023) carry += sm[1023];
        __syncthreads();
    }
    if (threadIdx.x == 0) rowptr[n] = carry;
}

__global__ __launch_bounds__(256) void scatter_kernel(const int* __restrict__ src,
                                                      const int* __restrict__ dst, int E,
                                                      int* __restrict__ cursor,
                                                      int2* __restrict__ el2) {
    int e = blockIdx.x * 256 + threadIdx.x;
    if (e < E) {
        int p = atomicAdd(&cursor[dst[e]], 1);
        el2[p] = make_int2(src[e], e);
    }
}

// ---------------- f32 GEMM 128x128 tile, BK=16, 8x8 per thread ----------------
// Y[M,N] = A[M,K] @ W[K,N] + bias[N]; N tile exactly 128; K multiple of 16.
__global__ __launch_bounds__(256) void gemm128(const float* __restrict__ A,
                                               const float* __restrict__ W,
                                               const float* __restrict__ bias,
                                               float* __restrict__ Y,
                                               int M, int N, int K) {
    __shared__ float As[16][132];  // [k][m]
    __shared__ float Ws[16][132];  // [k][n]
    const int tid = threadIdx.x;
    const int m0 = blockIdx.x * 128, n0 = blockIdx.y * 128;
    const int ar = tid >> 1, ak = (tid & 1) << 3;   // A: row 0..127, k-off 0/8
    const int wr = tid >> 4, wn = (tid & 15) << 3;  // W: k-row 0..15, col-off
    const int ty = tid >> 4, tx = tid & 15;
    const bool arow_ok = (m0 + ar) < M;
    float acc[8][8] = {{0.f}};
    for (int k0 = 0; k0 < K; k0 += 16) {
        float4 a0 = {0.f,0.f,0.f,0.f}, a1 = {0.f,0.f,0.f,0.f};
        if (arow_ok) {
            const float* ap = A + (size_t)(m0 + ar) * K + k0 + ak;
            a0 = ldf4(ap); a1 = ldf4(ap + 4);
        }
        const float* wp = W + (size_t)(k0 + wr) * N + n0 + wn;
        const float4 w0 = ldf4(wp), w1 = ldf4(wp + 4);
        __syncthreads();
        As[ak + 0][ar] = a0.x; As[ak + 1][ar] = a0.y;
        As[ak + 2][ar] = a0.z; As[ak + 3][ar] = a0.w;
        As[ak + 4][ar] = a1.x; As[ak + 5][ar] = a1.y;
        As[ak + 6][ar] = a1.z; As[ak + 7][ar] = a1.w;
        *reinterpret_cast<float4*>(&Ws[wr][wn]) = w0;
        *reinterpret_cast<float4*>(&Ws[wr][wn + 4]) = w1;
        __syncthreads();
#pragma unroll
        for (int kk = 0; kk < 16; ++kk) {
            float4 av0 = ldf4(&As[kk][ty * 4]);
            float4 av1 = ldf4(&As[kk][64 + ty * 4]);
            float4 bv0 = ldf4(&Ws[kk][tx * 4]);
            float4 bv1 = ldf4(&Ws[kk][64 + tx * 4]);
            float aa[8] = {av0.x, av0.y, av0.z, av0.w, av1.x, av1.y, av1.z, av1.w};
            float bb[8] = {bv0.x, bv0.y, bv0.z, bv0.w, bv1.x, bv1.y, bv1.z, bv1.w};
#pragma unroll
            for (int i = 0; i < 8; ++i)
#pragma unroll
                for (int j = 0; j < 8; ++j)
                    acc[i][j] = fmaf(aa[i], bb[j], acc[i][j]);
        }
    }
    const float4 bb0 = ldf4(bias + n0 + tx * 4);
    const float4 bb1 = ldf4(bias + n0 + 64 + tx * 4);
#pragma unroll
    for (int i = 0; i < 8; ++i) {
        const int m = m0 + ((i < 4) ? (ty * 4 + i) : (64 + ty * 4 + i - 4));
        if (m < M) {
            float4 o0, o1;
            o0.x = acc[i][0] + bb0.x; o0.y = acc[i][1] + bb0.y;
            o0.z = acc[i][2] + bb0.z; o0.w = acc[i][3] + bb0.w;
            o1.x = acc[i][4] + bb1.x; o1.y = acc[i][5] + bb1.y;
            o1.z = acc[i][6] + bb1.z; o1.w = acc[i][7] + bb1.w;
            float* yp = Y + (size_t)m * N + n0;
            *reinterpret_cast<float4*>(yp + tx * 4) = o0;
            *reinterpret_cast<float4*>(yp + 64 + tx * 4) = o1;
        }
    }
}

// ---------------- small-N GEMM (N=32) ----------------
__global__ __launch_bounds__(256) void gemm_bias(const float* __restrict__ A,
                                                 const float* __restrict__ W,
                                                 const float* __restrict__ bias,
                                                 float* __restrict__ Y,
                                                 int M, int N, int K) {
    __shared__ float As[16][68];
    __shared__ float Ws[16][68];
    const int tid = threadIdx.x;
    const int tx = tid & 15, ty = tid >> 4;
    const int m0 = blockIdx.x * 64, n0 = blockIdx.y * 64;
    const int lm = tid >> 2;
    const int lk = (tid & 3) << 2;
    const int wk = tid >> 4;
    const int wn = (tid & 15) << 2;
    float acc[4][4] = {{0.f}};
    for (int k0 = 0; k0 < K; k0 += 16) {
        float4 a = {0.f, 0.f, 0.f, 0.f};
        if (m0 + lm < M) a = ldf4(A + (size_t)(m0 + lm) * K + k0 + lk);
        As[lk + 0][lm] = a.x; As[lk + 1][lm] = a.y;
        As[lk + 2][lm] = a.z; As[lk + 3][lm] = a.w;
        float4 w = {0.f, 0.f, 0.f, 0.f};
        if (n0 + wn < N) w = ldf4(W + (size_t)(k0 + wk) * N + n0 + wn);
        *reinterpret_cast<float4*>(&Ws[wk][wn]) = w;
        __syncthreads();
#pragma unroll
        for (int kk = 0; kk < 16; ++kk) {
            float4 av = *reinterpret_cast<const float4*>(&As[kk][ty << 2]);
            float4 bv = *reinterpret_cast<const float4*>(&Ws[kk][tx << 2]);
            float aa[4] = {av.x, av.y, av.z, av.w};
            float bb[4] = {bv.x, bv.y, bv.z, bv.w};
#pragma unroll
            for (int i = 0; i < 4; ++i)
#pragma unroll
                for (int j = 0; j < 4; ++j)
                    acc[i][j] = fmaf(aa[i], bb[j], acc[i][j]);
        }
        __syncthreads();
    }
    if (n0 + (tx << 2) < N) {
        float4 bb = ldf4(bias + n0 + (tx << 2));
#pragma unroll
        for (int i = 0; i < 4; ++i) {
            int m = m0 + (ty << 2) + i;
            if (m < M) {
                float4 o;
                o.x = acc[i][0] + bb.x; o.y = acc[i][1] + bb.y;
                o.z = acc[i][2] + bb.z; o.w = acc[i][3] + bb.w;
                *reinterpret_cast<float4*>(Y + (size_t)m * N + n0 + (tx << 2)) = o;
            }
        }
    }
}

// ---------------- fused attention: one wave per dst node ----------------
// lane owns hc = 4*lane..4*lane+3 ; head h = lane>>3 ; edge-dim slice d0 = (lane&7)*4
// MODE 0: conv1 epilogue (skip + relu + LayerNorm) -> hout [N,256]
// MODE 1: conv2 epilogue (head-mean + skip2 + relu + final 32->2 linear) -> out [N,2]
template <int MODE>
__global__ __launch_bounds__(256) void attn_kernel(
    const float* __restrict__ q, const float* __restrict__ k,
    const float* __restrict__ v, const float* __restrict__ skipb,
    const float* __restrict__ ea, const float* __restrict__ we,
    const int2* __restrict__ el2, const int* __restrict__ rowptr,
    const float* __restrict__ pa, const float* __restrict__ pb,
    float* __restrict__ outp, int nN) {
    const int wid = threadIdx.x >> 6, lane = threadIdx.x & 63;
    const int node = blockIdx.x * 4 + wid;
    if (node >= nN) return;
    const int hc0 = lane << 2;
    const int h = lane >> 3;
    const int d0 = (lane & 7) << 2;

    const float4 qv = ldf4(q + (size_t)node * HC_DIM + hc0);
    // prologue: P4[dd] = P[h, d0+dd] = sum_c q[h,c] * we[d0+dd, h*32+c]
    float P4[4] = {0.f, 0.f, 0.f, 0.f};
#pragma unroll
    for (int j = 0; j < 8; ++j) {
        float qx = __shfl(qv.x, j, 8), qy = __shfl(qv.y, j, 8);
        float qz = __shfl(qv.z, j, 8), qw = __shfl(qv.w, j, 8);
        const float* wrow = we + h * 32 + j * 4;
#pragma unroll
        for (int dd = 0; dd < 4; ++dd) {
            float4 wv = ldf4(wrow + (size_t)(d0 + dd) * HC_DIM);
            P4[dd] = fmaf(qx, wv.x, fmaf(qy, wv.y, fmaf(qz, wv.z, fmaf(qw, wv.w, P4[dd]))));
        }
    }

    const float* kb = k + hc0;
    const float* vb = v + hc0;
    const float* ab = ea + d0;

    float m = -INFINITY, denom = 0.f;
    float ax = 0.f, ay = 0.f, az = 0.f, aw = 0.f;
    float A4[4] = {0.f, 0.f, 0.f, 0.f};
    const int e0 = rowptr[node], e1 = rowptr[node + 1];
    for (int cb = e0; cb < e1; cb += 64) {
        const int cnt = min(64, e1 - cb);
        const int2 ee = el2[cb + min(lane, cnt - 1)];  // one load covers 64 edges
        for (int g = 0; g < cnt; g += 8) {
            float4 ku4[8], vu4[8], au4[8];
#pragma unroll
            for (int u = 0; u < 8; ++u) {
                const int jj = (g + u < cnt) ? (g + u) : (cnt - 1);
                const int s  = __shfl(ee.x, jj);
                const int e2 = __shfl(ee.y, jj);
                ku4[u] = ldf4(kb + (size_t)s * HC_DIM);
                vu4[u] = ldf4(vb + (size_t)s * HC_DIM);
                au4[u] = ldf4(ab + (size_t)e2 * E_DIM);
            }
            float lg[8];
#pragma unroll
            for (int u = 0; u < 8; ++u) {
                float lp = qv.x * ku4[u].x + qv.y * ku4[u].y +
                           qv.z * ku4[u].z + qv.w * ku4[u].w +
                           au4[u].x * P4[0] + au4[u].y * P4[1] +
                           au4[u].z * P4[2] + au4[u].w * P4[3];
                lp += __shfl_xor(lp, 1); lp += __shfl_xor(lp, 2); lp += __shfl_xor(lp, 4);
                lg[u] = lp * 0.17677669529663687f;  // 1/sqrt(32)
            }
            float gm = lg[0];
#pragma unroll
            for (int u = 1; u < 8; ++u) gm = fmaxf(gm, lg[u]);
            float wu[8], gs = 0.f;
#pragma unroll
            for (int u = 0; u < 8; ++u) {
                wu[u] = (g + u < cnt) ? __expf(lg[u] - gm) : 0.f;
                gs += wu[u];
            }
            float gax = 0.f, gay = 0.f, gaz = 0.f, gaw = 0.f;
            float gA0 = 0.f, gA1 = 0.f, gA2 = 0.f, gA3 = 0.f;
#pragma unroll
            for (int u = 0; u < 8; ++u) {
                gax = fmaf(wu[u], vu4[u].x, gax);
                gay = fmaf(wu[u], vu4[u].y, gay);
                gaz = fmaf(wu[u], vu4[u].z, gaz);
                gaw = fmaf(wu[u], vu4[u].w, gaw);
                gA0 = fmaf(wu[u], au4[u].x, gA0);
                gA1 = fmaf(wu[u], au4[u].y, gA1);
                gA2 = fmaf(wu[u], au4[u].z, gA2);
                gA3 = fmaf(wu[u], au4[u].w, gA3);
            }
            const float mn = fmaxf(m, gm);
            const float sc = __expf(m - mn);
            const float gsc = __expf(gm - mn);
            denom = denom * sc + gs * gsc;
            ax = ax * sc + gax * gsc;
            ay = ay * sc + gay * gsc;
            az = az * sc + gaz * gsc;
            aw = aw * sc + gaw * gsc;
            A4[0] = A4[0] * sc + gA0 * gsc;
            A4[1] = A4[1] * sc + gA1 * gsc;
            A4[2] = A4[2] * sc + gA2 * gsc;
            A4[3] = A4[3] * sc + gA3 * gsc;
            m = mn;
        }
    }
    // epilogue: edge-message part = A[h,:] @ we[:, hc0..hc0+3]
    float mx = 0.f, my = 0.f, mz = 0.f, mw = 0.f;
#pragma unroll
    for (int j = 0; j < 8; ++j) {
        float a0 = __shfl(A4[0], j, 8), a1 = __shfl(A4[1], j, 8);
        float a2 = __shfl(A4[2], j, 8), a3 = __shfl(A4[3], j, 8);
        const float* wrow = we + (size_t)(j * 4) * HC_DIM + hc0;
        float4 w0 = ldf4(wrow);
        float4 w1 = ldf4(wrow + HC_DIM);
        float4 w2 = ldf4(wrow + 2 * HC_DIM);
        float4 w3 = ldf4(wrow + 3 * HC_DIM);
        mx += a0 * w0.x + a1 * w1.x + a2 * w2.x + a3 * w3.x;
        my += a0 * w0.y + a1 * w1.y + a2 * w2.y + a3 * w3.y;
        mz += a0 * w0.z + a1 * w1.z + a2 * w2.z + a3 * w3.z;
        mw += a0 * w0.w + a1 * w1.w + a2 * w2.w + a3 * w3.w;
    }
    const float inv = 1.f / (denom + 1e-16f);

    if (MODE == 0) {
        const float4 sk = ldf4(skipb + (size_t)node * HC_DIM + hc0);
        float ox = fmaxf((ax + mx) * inv + sk.x, 0.f);
        float oy = fmaxf((ay + my) * inv + sk.y, 0.f);
        float oz = fmaxf((az + mz) * inv + sk.z, 0.f);
        float ow = fmaxf((aw + mw) * inv + sk.w, 0.f);
        float s1 = ox + oy + oz + ow;
        float s2 = ox * ox + oy * oy + oz * oz + ow * ow;
#pragma unroll
        for (int msk = 1; msk < 64; msk <<= 1) {
            s1 += __shfl_xor(s1, msk);
            s2 += __shfl_xor(s2, msk);
        }
        const float mu = s1 * (1.f / 256.f);
        const float var = s2 * (1.f / 256.f) - mu * mu;
        const float rstd = rsqrtf(var + 1e-5f);
        const float4 gv = ldf4(pa + hc0);
        const float4 bv = ldf4(pb + hc0);
        float4 o;
        o.x = (ox - mu) * rstd * gv.x + bv.x;
        o.y = (oy - mu) * rstd * gv.y + bv.y;
        o.z = (oz - mu) * rstd * gv.z + bv.z;
        o.w = (ow - mu) * rstd * gv.w + bv.w;
        *reinterpret_cast<float4*>(outp + (size_t)node * HC_DIM + hc0) = o;
    } else {
        float ox = (ax + mx) * inv, oy = (ay + my) * inv;
        float oz = (az + mz) * inv, ow = (aw + mw) * inv;
#pragma unroll
        for (int msk = 8; msk < 64; msk <<= 1) {
            ox += __shfl_xor(ox, msk);
            oy += __shfl_xor(oy, msk);
            oz += __shfl_xor(oz, msk);
            ow += __shfl_xor(ow, msk);
        }
        const int c0 = (lane & 7) << 2;
        const float4 sk = ldf4(skipb + (size_t)node * C_DIM + c0);
        const float yx = fmaxf(ox * 0.125f + sk.x, 0.f);
        const float yy = fmaxf(oy * 0.125f + sk.y, 0.f);
        const float yz = fmaxf(oz * 0.125f + sk.z, 0.f);
        const float yw = fmaxf(ow * 0.125f + sk.w, 0.f);
        float p0 = yx * pa[(c0 + 0) * 2 + 0] + yy * pa[(c0 + 1) * 2 + 0] +
                   yz * pa[(c0 + 2) * 2 + 0] + yw * pa[(c0 + 3) * 2 + 0];
        float p1 = yx * pa[(c0 + 0) * 2 + 1] + yy * pa[(c0 + 1) * 2 + 1] +
                   yz * pa[(c0 + 2) * 2 + 1] + yw * pa[(c0 + 3) * 2 + 1];
#pragma unroll
        for (int msk = 1; msk < 8; msk <<= 1) {
            p0 += __shfl_xor(p0, msk);
            p1 += __shfl_xor(p1, msk);
        }
        if (lane == 0) {
            outp[(size_t)node * 2 + 0] = p0 + pb[0];
            outp[(size_t)node * 2 + 1] = p1 + pb[1];
        }
    }
}

extern "C" void kernel_launch(void* const* d_in, const int* in_sizes, int n_in,
                              void* d_out, int out_size, void* d_ws, size_t ws_size,
                              hipStream_t stream) {
    const float* x        = (const float*)d_in[0];
    const int*   eidx     = (const int*)d_in[1];
    const float* eattr    = (const float*)d_in[2];
    const float* wq1      = (const float*)d_in[3];
    const float* bq1      = (const float*)d_in[4];
    const float* wk1      = (const float*)d_in[5];
    const float* bk1      = (const float*)d_in[6];
    const float* wv1      = (const float*)d_in[7];
    const float* bv1      = (const float*)d_in[8];
    const float* we1      = (const float*)d_in[9];
    const float* wskip1   = (const float*)d_in[10];
    const float* bskip1   = (const float*)d_in[11];
    const float* g1       = (const float*)d_in[12];
    const float* b1       = (const float*)d_in[13];
    const float* wq2      = (const float*)d_in[14];
    const float* bq2      = (const float*)d_in[15];
    const float* wk2      = (const float*)d_in[16];
    const float* bk2      = (const float*)d_in[17];
    const float* wv2      = (const float*)d_in[18];
    const float* bv2      = (const float*)d_in[19];
    const float* we2      = (const float*)d_in[20];
    const float* wskip2   = (const float*)d_in[21];
    const float* bskip2   = (const float*)d_in[22];
    const float* wc       = (const float*)d_in[23];
    const float* bc       = (const float*)d_in[24];

    const int N = in_sizes[0] / 128;
    const int E = in_sizes[2] / 32;
    const int* src = eidx;
    const int* dst = eidx + E;
    float* out = (float*)d_out;

    char* ws = (char*)d_ws;
    const size_t fbytes = (size_t)N * HC_DIM * sizeof(float);
    float* qb = (float*)(ws + 0 * fbytes);
    float* kb = (float*)(ws + 1 * fbytes);
    float* vb = (float*)(ws + 2 * fbytes);
    float* sb = (float*)(ws + 3 * fbytes);  // skip1 [N,256] / skip2 [N,32]
    float* hb = (float*)(ws + 4 * fbytes);
    int* rowptr = (int*)(ws + 5 * fbytes);
    int* cursor = rowptr + (N + 1);
    int2* el2   = (int2*)(cursor + N + 1);  // 8B-aligned

    // CSR build
    hipMemsetAsync(cursor, 0, (size_t)N * sizeof(int), stream);
    count_kernel<<<dim3((E + 255) / 256), dim3(256), 0, stream>>>(dst, E, cursor);
    scan_kernel<<<dim3(1), dim3(1024), 0, stream>>>(cursor, rowptr, N);
    scatter_kernel<<<dim3((E + 255) / 256), dim3(256), 0, stream>>>(src, dst, E, cursor, el2);

    // conv1 projections (K=128, N=256)
    dim3 g1g((N + 127) / 128, 2);
    gemm128<<<g1g, dim3(256), 0, stream>>>(x, wq1, bq1, qb, N, 256, 128);
    gemm128<<<g1g, dim3(256), 0, stream>>>(x, wk1, bk1, kb, N, 256, 128);
    gemm128<<<g1g, dim3(256), 0, stream>>>(x, wv1, bv1, vb, N, 256, 128);
    gemm128<<<g1g, dim3(256), 0, stream>>>(x, wskip1, bskip1, sb, N, 256, 128);

    attn_kernel<0><<<dim3((N + 3) / 4), dim3(256), 0, stream>>>(
        qb, kb, vb, sb, eattr, we1, el2, rowptr, g1, b1, hb, N);

    // conv2 projections (K=256)
    gemm128<<<g1g, dim3(256), 0, stream>>>(hb, wq2, bq2, qb, N, 256, 256);
    gemm128<<<g1g, dim3(256), 0, stream>>>(hb, wk2, bk2, kb, N, 256, 256);
    gemm128<<<g1g, dim3(256), 0, stream>>>(hb, wv2, bv2, vb, N, 256, 256);
    gemm_bias<<<dim3((N + 63) / 64, 1), dim3(256), 0, stream>>>(hb, wskip2, bskip2, sb, N, 32, 256);

    attn_kernel<1><<<dim3((N + 3) / 4), dim3(256), 0, stream>>>(
        qb, kb, vb, sb, eattr, we2, el2, rowptr, wc, bc, out, N);
}

// Round 5
// 1426.750 us; speedup vs baseline: 1.1808x; 1.1350x over previous
//
#include <hip/hip_runtime.h>
#include <math.h>

#define HC_DIM 256
#define E_DIM 32

static __device__ __forceinline__ const float4& ldf4(const float* p) {
    return *reinterpret_cast<const float4*>(p);
}

// ---------------- CSR build ----------------
__global__ __launch_bounds__(256) void count_kernel(const int* __restrict__ dst, int E,
                                                    int* __restrict__ cnt) {
    int e = blockIdx.x * 256 + threadIdx.x;
    if (e < E) atomicAdd(&cnt[dst[e]], 1);
}

__global__ __launch_bounds__(1024) void scan_kernel(int* __restrict__ cnt,
                                                    int* __restrict__ rowptr, int n) {
    __shared__ int sm[1024];
    __shared__ int carry;
    if (threadIdx.x == 0) carry = 0;
    __syncthreads();
    for (int base = 0; base < n; base += 1024) {
        int i = base + (int)threadIdx.x;
        int val = (i < n) ? cnt[i] : 0;
        sm[threadIdx.x] = val;
        __syncthreads();
        for (int off = 1; off < 1024; off <<= 1) {
            int t = (threadIdx.x >= (unsigned)off) ? sm[threadIdx.x - off] : 0;
            __syncthreads();
            sm[threadIdx.x] += t;
            __syncthreads();
        }
        int incl = sm[threadIdx.x];
        int excl = carry + incl - val;
        if (i < n) { rowptr[i] = excl; cnt[i] = excl; }
        __syncthreads();
        if (threadIdx.x == 1023) carry += sm[1023];
        __syncthreads();
    }
    if (threadIdx.x == 0) rowptr[n] = carry;
}

__global__ __launch_bounds__(256) void scatter_kernel(const int* __restrict__ src,
                                                      const int* __restrict__ dst, int E,
                                                      int* __restrict__ cursor,
                                                      int2* __restrict__ el2) {
    int e = blockIdx.x * 256 + threadIdx.x;
    if (e < E) {
        int p = atomicAdd(&cursor[dst[e]], 1);
        el2[p] = make_int2(src[e], e);
    }
}

// ---------------- weight fold: WqP[r, h*32+d] = sum_c wq[r,h*32+c]*we[d,h*32+c] ----------------
// row r == K encodes the bias fold (bqP).
__global__ __launch_bounds__(256) void wfold_kernel(const float* __restrict__ wq,
                                                    const float* __restrict__ bq,
                                                    const float* __restrict__ we,
                                                    float* __restrict__ WqP,
                                                    float* __restrict__ bqP, int K) {
    int t = blockIdx.x * 256 + threadIdx.x;
    if (t >= (K + 1) * 256) return;
    int r = t >> 8, col = t & 255;
    int h = col >> 5, d = col & 31;
    const float* srow = (r < K) ? (wq + (size_t)r * HC_DIM + h * 32) : (bq + h * 32);
    const float* wrow = we + (size_t)d * HC_DIM + h * 32;
    float s = 0.f;
#pragma unroll
    for (int c4 = 0; c4 < 8; ++c4) {
        float4 a = ldf4(srow + c4 * 4);
        float4 b = ldf4(wrow + c4 * 4);
        s += a.x * b.x + a.y * b.y + a.z * b.z + a.w * b.w;
    }
    if (r < K) WqP[(size_t)r * HC_DIM + col] = s;
    else bqP[col] = s;
}

// ---------------- f32 GEMM 128x128 tile, BK=16, 8x8 per thread ----------------
__global__ __launch_bounds__(256) void gemm128(const float* __restrict__ A,
                                               const float* __restrict__ W,
                                               const float* __restrict__ bias,
                                               float* __restrict__ Y,
                                               int M, int N, int K) {
    __shared__ float As[16][132];
    __shared__ float Ws[16][132];
    const int tid = threadIdx.x;
    const int m0 = blockIdx.x * 128, n0 = blockIdx.y * 128;
    const int ar = tid >> 1, ak = (tid & 1) << 3;
    const int wr = tid >> 4, wn = (tid & 15) << 3;
    const int ty = tid >> 4, tx = tid & 15;
    const bool arow_ok = (m0 + ar) < M;
    float acc[8][8] = {{0.f}};
    for (int k0 = 0; k0 < K; k0 += 16) {
        float4 a0 = {0.f,0.f,0.f,0.f}, a1 = {0.f,0.f,0.f,0.f};
        if (arow_ok) {
            const float* ap = A + (size_t)(m0 + ar) * K + k0 + ak;
            a0 = ldf4(ap); a1 = ldf4(ap + 4);
        }
        const float* wp = W + (size_t)(k0 + wr) * N + n0 + wn;
        const float4 w0 = ldf4(wp), w1 = ldf4(wp + 4);
        __syncthreads();
        As[ak + 0][ar] = a0.x; As[ak + 1][ar] = a0.y;
        As[ak + 2][ar] = a0.z; As[ak + 3][ar] = a0.w;
        As[ak + 4][ar] = a1.x; As[ak + 5][ar] = a1.y;
        As[ak + 6][ar] = a1.z; As[ak + 7][ar] = a1.w;
        *reinterpret_cast<float4*>(&Ws[wr][wn]) = w0;
        *reinterpret_cast<float4*>(&Ws[wr][wn + 4]) = w1;
        __syncthreads();
#pragma unroll
        for (int kk = 0; kk < 16; ++kk) {
            float4 av0 = ldf4(&As[kk][ty * 4]);
            float4 av1 = ldf4(&As[kk][64 + ty * 4]);
            float4 bv0 = ldf4(&Ws[kk][tx * 4]);
            float4 bv1 = ldf4(&Ws[kk][64 + tx * 4]);
            float aa[8] = {av0.x, av0.y, av0.z, av0.w, av1.x, av1.y, av1.z, av1.w};
            float bb[8] = {bv0.x, bv0.y, bv0.z, bv0.w, bv1.x, bv1.y, bv1.z, bv1.w};
#pragma unroll
            for (int i = 0; i < 8; ++i)
#pragma unroll
                for (int j = 0; j < 8; ++j)
                    acc[i][j] = fmaf(aa[i], bb[j], acc[i][j]);
        }
    }
    const float4 bb0 = ldf4(bias + n0 + tx * 4);
    const float4 bb1 = ldf4(bias + n0 + 64 + tx * 4);
#pragma unroll
    for (int i = 0; i < 8; ++i) {
        const int m = m0 + ((i < 4) ? (ty * 4 + i) : (64 + ty * 4 + i - 4));
        if (m < M) {
            float4 o0, o1;
            o0.x = acc[i][0] + bb0.x; o0.y = acc[i][1] + bb0.y;
            o0.z = acc[i][2] + bb0.z; o0.w = acc[i][3] + bb0.w;
            o1.x = acc[i][4] + bb1.x; o1.y = acc[i][5] + bb1.y;
            o1.z = acc[i][6] + bb1.z; o1.w = acc[i][7] + bb1.w;
            float* yp = Y + (size_t)m * N + n0;
            *reinterpret_cast<float4*>(yp + tx * 4) = o0;
            *reinterpret_cast<float4*>(yp + 64 + tx * 4) = o1;
        }
    }
}

// ---------------- small-N GEMM (N=32) ----------------
__global__ __launch_bounds__(256) void gemm_bias(const float* __restrict__ A,
                                                 const float* __restrict__ W,
                                                 const float* __restrict__ bias,
                                                 float* __restrict__ Y,
                                                 int M, int N, int K) {
    __shared__ float As[16][68];
    __shared__ float Ws[16][68];
    const int tid = threadIdx.x;
    const int tx = tid & 15, ty = tid >> 4;
    const int m0 = blockIdx.x * 64, n0 = blockIdx.y * 64;
    const int lm = tid >> 2;
    const int lk = (tid & 3) << 2;
    const int wk = tid >> 4;
    const int wn = (tid & 15) << 2;
    float acc[4][4] = {{0.f}};
    for (int k0 = 0; k0 < K; k0 += 16) {
        float4 a = {0.f, 0.f, 0.f, 0.f};
        if (m0 + lm < M) a = ldf4(A + (size_t)(m0 + lm) * K + k0 + lk);
        As[lk + 0][lm] = a.x; As[lk + 1][lm] = a.y;
        As[lk + 2][lm] = a.z; As[lk + 3][lm] = a.w;
        float4 w = {0.f, 0.f, 0.f, 0.f};
        if (n0 + wn < N) w = ldf4(W + (size_t)(k0 + wk) * N + n0 + wn);
        *reinterpret_cast<float4*>(&Ws[wk][wn]) = w;
        __syncthreads();
#pragma unroll
        for (int kk = 0; kk < 16; ++kk) {
            float4 av = *reinterpret_cast<const float4*>(&As[kk][ty << 2]);
            float4 bv = *reinterpret_cast<const float4*>(&Ws[kk][tx << 2]);
            float aa[4] = {av.x, av.y, av.z, av.w};
            float bb[4] = {bv.x, bv.y, bv.z, bv.w};
#pragma unroll
            for (int i = 0; i < 4; ++i)
#pragma unroll
                for (int j = 0; j < 4; ++j)
                    acc[i][j] = fmaf(aa[i], bb[j], acc[i][j]);
        }
        __syncthreads();
    }
    if (n0 + (tx << 2) < N) {
        float4 bb = ldf4(bias + n0 + (tx << 2));
#pragma unroll
        for (int i = 0; i < 4; ++i) {
            int m = m0 + (ty << 2) + i;
            if (m < M) {
                float4 o;
                o.x = acc[i][0] + bb.x; o.y = acc[i][1] + bb.y;
                o.z = acc[i][2] + bb.z; o.w = acc[i][3] + bb.w;
                *reinterpret_cast<float4*>(Y + (size_t)m * N + n0 + (tx << 2)) = o;
            }
        }
    }
}

// ---------------- edge-gather attention core: one wave per dst node ----------------
// lane owns hc = 4*lane..4*lane+3 ; head h = lane>>3 ; edge-dim slice d0 = (lane&7)*4
// Pm row layout: P[n, h*32+d] -> lane reads at offset hc0 (== h*32+d0). No we-table reads.
// Writes accV = (sum alpha*v) and accA = (sum alpha*ea), both already divided by denom.
__global__ __launch_bounds__(256) void attn_kernel(
    const float* __restrict__ q, const float* __restrict__ Pm,
    const float* __restrict__ k, const float* __restrict__ v,
    const float* __restrict__ ea,
    const int2* __restrict__ el2, const int* __restrict__ rowptr,
    float* __restrict__ accV, float* __restrict__ accA, int nN) {
    const int wid = threadIdx.x >> 6, lane = threadIdx.x & 63;
    const int node = blockIdx.x * 4 + wid;
    if (node >= nN) return;
    const int hc0 = lane << 2;
    const int d0 = (lane & 7) << 2;

    const float4 qv = ldf4(q + (size_t)node * HC_DIM + hc0);
    const float4 Pv = ldf4(Pm + (size_t)node * HC_DIM + hc0);
    const float* kb = k + hc0;
    const float* vb = v + hc0;
    const float* ab = ea + d0;

    float m = -INFINITY, denom = 0.f;
    float ax = 0.f, ay = 0.f, az = 0.f, aw = 0.f;
    float A0 = 0.f, A1 = 0.f, A2 = 0.f, A3 = 0.f;
    const int e0 = rowptr[node], e1 = rowptr[node + 1];
    for (int cb = e0; cb < e1; cb += 64) {
        const int cnt = min(64, e1 - cb);
        const int2 ee = el2[cb + min(lane, cnt - 1)];  // one load covers 64 edges
        for (int g = 0; g < cnt; g += 8) {
            float4 ku4[8], vu4[8], au4[8];
#pragma unroll
            for (int u = 0; u < 8; ++u) {
                const int jj = (g + u < cnt) ? (g + u) : (cnt - 1);
                const int s  = __shfl(ee.x, jj);
                const int e2 = __shfl(ee.y, jj);
                ku4[u] = ldf4(kb + (size_t)s * HC_DIM);
                vu4[u] = ldf4(vb + (size_t)s * HC_DIM);
                au4[u] = ldf4(ab + (size_t)e2 * E_DIM);
            }
            float lg[8];
#pragma unroll
            for (int u = 0; u < 8; ++u) {
                float lp = qv.x * ku4[u].x + qv.y * ku4[u].y +
                           qv.z * ku4[u].z + qv.w * ku4[u].w +
                           au4[u].x * Pv.x + au4[u].y * Pv.y +
                           au4[u].z * Pv.z + au4[u].w * Pv.w;
                lp += __shfl_xor(lp, 1); lp += __shfl_xor(lp, 2); lp += __shfl_xor(lp, 4);
                lg[u] = lp * 0.17677669529663687f;  // 1/sqrt(32)
            }
            float gm = lg[0];
#pragma unroll
            for (int u = 1; u < 8; ++u) gm = fmaxf(gm, lg[u]);
            float wu[8], gs = 0.f;
#pragma unroll
            for (int u = 0; u < 8; ++u) {
                wu[u] = (g + u < cnt) ? __expf(lg[u] - gm) : 0.f;
                gs += wu[u];
            }
            float gax = 0.f, gay = 0.f, gaz = 0.f, gaw = 0.f;
            float gA0 = 0.f, gA1 = 0.f, gA2 = 0.f, gA3 = 0.f;
#pragma unroll
            for (int u = 0; u < 8; ++u) {
                gax = fmaf(wu[u], vu4[u].x, gax);
                gay = fmaf(wu[u], vu4[u].y, gay);
                gaz = fmaf(wu[u], vu4[u].z, gaz);
                gaw = fmaf(wu[u], vu4[u].w, gaw);
                gA0 = fmaf(wu[u], au4[u].x, gA0);
                gA1 = fmaf(wu[u], au4[u].y, gA1);
                gA2 = fmaf(wu[u], au4[u].z, gA2);
                gA3 = fmaf(wu[u], au4[u].w, gA3);
            }
            const float mn = fmaxf(m, gm);
            const float sc = __expf(m - mn);
            const float gsc = __expf(gm - mn);
            denom = denom * sc + gs * gsc;
            ax = ax * sc + gax * gsc;
            ay = ay * sc + gay * gsc;
            az = az * sc + gaz * gsc;
            aw = aw * sc + gaw * gsc;
            A0 = A0 * sc + gA0 * gsc;
            A1 = A1 * sc + gA1 * gsc;
            A2 = A2 * sc + gA2 * gsc;
            A3 = A3 * sc + gA3 * gsc;
            m = mn;
        }
    }
    const float inv = 1.f / (denom + 1e-16f);
    float4 oV, oA;
    oV.x = ax * inv; oV.y = ay * inv; oV.z = az * inv; oV.w = aw * inv;
    oA.x = A0 * inv; oA.y = A1 * inv; oA.z = A2 * inv; oA.w = A3 * inv;
    *reinterpret_cast<float4*>(accV + (size_t)node * HC_DIM + hc0) = oV;
    *reinterpret_cast<float4*>(accA + (size_t)node * HC_DIM + hc0) = oA;
}

// ---------------- per-head epilogue GEMM: Z = accV + accA @ we (+skip) ----------------
// thread owns column c; head h=c>>5; we column cached in 32 regs; accA tile in LDS.
__global__ __launch_bounds__(256) void headgemm_kernel(
    const float* __restrict__ accV, const float* __restrict__ accA,
    const float* __restrict__ skipb, const float* __restrict__ we,
    float* __restrict__ Z, int nN) {
    __shared__ float Al[32][256];
    const int tid = threadIdx.x;
    const int n0 = blockIdx.x * 32;
    const int c = tid;
    const int h = c >> 5;
    float wreg[32];
#pragma unroll
    for (int d = 0; d < 32; ++d) wreg[d] = we[(size_t)d * HC_DIM + c];
    const int rows = min(32, nN - n0);
#pragma unroll
    for (int i = 0; i < 8; ++i) {
        const int f4 = i * 256 + tid;
        const int r = f4 >> 6, c4 = (f4 & 63) << 2;
        float4 a = (r < rows) ? ldf4(accA + (size_t)(n0 + r) * HC_DIM + c4)
                              : make_float4(0.f, 0.f, 0.f, 0.f);
        *reinterpret_cast<float4*>(&Al[r][c4]) = a;
    }
    __syncthreads();
    for (int n = 0; n < rows; ++n) {
        const float* arow = &Al[n][h * 32];
        float s = 0.f;
#pragma unroll
        for (int d4 = 0; d4 < 8; ++d4) {
            const float4 a = *reinterpret_cast<const float4*>(arow + d4 * 4);
            s += a.x * wreg[d4 * 4 + 0] + a.y * wreg[d4 * 4 + 1] +
                 a.z * wreg[d4 * 4 + 2] + a.w * wreg[d4 * 4 + 3];
        }
        const size_t off = (size_t)(n0 + n) * HC_DIM + c;
        float z = accV[off] + s;
        if (skipb) z += skipb[off];
        Z[off] = z;
    }
}

// ---------------- conv1 epilogue: relu + LayerNorm ----------------
__global__ __launch_bounds__(256) void ln_kernel(
    const float* __restrict__ Z, const float* __restrict__ g,
    const float* __restrict__ b, float* __restrict__ hout, int nN) {
    const int wid = threadIdx.x >> 6, lane = threadIdx.x & 63;
    const int node = blockIdx.x * 4 + wid;
    if (node >= nN) return;
    const int hc0 = lane << 2;
    const float4 z = ldf4(Z + (size_t)node * HC_DIM + hc0);
    const float ox = fmaxf(z.x, 0.f), oy = fmaxf(z.y, 0.f);
    const float oz = fmaxf(z.z, 0.f), ow = fmaxf(z.w, 0.f);
    float s1 = ox + oy + oz + ow;
    float s2 = ox * ox + oy * oy + oz * oz + ow * ow;
#pragma unroll
    for (int msk = 1; msk < 64; msk <<= 1) {
        s1 += __shfl_xor(s1, msk);
        s2 += __shfl_xor(s2, msk);
    }
    const float mu = s1 * (1.f / 256.f);
    const float var = s2 * (1.f / 256.f) - mu * mu;
    const float rstd = rsqrtf(var + 1e-5f);
    const float4 gv = ldf4(g + hc0);
    const float4 bv = ldf4(b + hc0);
    float4 o;
    o.x = (ox - mu) * rstd * gv.x + bv.x;
    o.y = (oy - mu) * rstd * gv.y + bv.y;
    o.z = (oz - mu) * rstd * gv.z + bv.z;
    o.w = (ow - mu) * rstd * gv.w + bv.w;
    *reinterpret_cast<float4*>(hout + (size_t)node * HC_DIM + hc0) = o;
}

// ---------------- conv2 epilogue: head-mean + skip2 + relu + final 32->2 linear ----------------
__global__ __launch_bounds__(256) void final_kernel(
    const float* __restrict__ Z2, const float* __restrict__ skip2,
    const float* __restrict__ wc, const float* __restrict__ bc,
    float* __restrict__ out, int nN) {
    const int wid = threadIdx.x >> 6, lane = threadIdx.x & 63;
    const int node = blockIdx.x * 4 + wid;
    if (node >= nN) return;
    const int hc0 = lane << 2;
    const float4 z = ldf4(Z2 + (size_t)node * HC_DIM + hc0);
    float ox = z.x, oy = z.y, oz = z.z, ow = z.w;
#pragma unroll
    for (int msk = 8; msk < 64; msk <<= 1) {
        ox += __shfl_xor(ox, msk);
        oy += __shfl_xor(oy, msk);
        oz += __shfl_xor(oz, msk);
        ow += __shfl_xor(ow, msk);
    }
    const int c0 = (lane & 7) << 2;
    const float4 sk = ldf4(skip2 + (size_t)node * 32 + c0);
    const float yx = fmaxf(ox * 0.125f + sk.x, 0.f);
    const float yy = fmaxf(oy * 0.125f + sk.y, 0.f);
    const float yz = fmaxf(oz * 0.125f + sk.z, 0.f);
    const float yw = fmaxf(ow * 0.125f + sk.w, 0.f);
    float p0 = yx * wc[(c0 + 0) * 2 + 0] + yy * wc[(c0 + 1) * 2 + 0] +
               yz * wc[(c0 + 2) * 2 + 0] + yw * wc[(c0 + 3) * 2 + 0];
    float p1 = yx * wc[(c0 + 0) * 2 + 1] + yy * wc[(c0 + 1) * 2 + 1] +
               yz * wc[(c0 + 2) * 2 + 1] + yw * wc[(c0 + 3) * 2 + 1];
#pragma unroll
    for (int msk = 1; msk < 8; msk <<= 1) {
        p0 += __shfl_xor(p0, msk);
        p1 += __shfl_xor(p1, msk);
    }
    if (lane == 0) {
        out[(size_t)node * 2 + 0] = p0 + bc[0];
        out[(size_t)node * 2 + 1] = p1 + bc[1];
    }
}

extern "C" void kernel_launch(void* const* d_in, const int* in_sizes, int n_in,
                              void* d_out, int out_size, void* d_ws, size_t ws_size,
                              hipStream_t stream) {
    const float* x        = (const float*)d_in[0];
    const int*   eidx     = (const int*)d_in[1];
    const float* eattr    = (const float*)d_in[2];
    const float* wq1      = (const float*)d_in[3];
    const float* bq1      = (const float*)d_in[4];
    const float* wk1      = (const float*)d_in[5];
    const float* bk1      = (const float*)d_in[6];
    const float* wv1      = (const float*)d_in[7];
    const float* bv1      = (const float*)d_in[8];
    const float* we1      = (const float*)d_in[9];
    const float* wskip1   = (const float*)d_in[10];
    const float* bskip1   = (const float*)d_in[11];
    const float* g1       = (const float*)d_in[12];
    const float* b1       = (const float*)d_in[13];
    const float* wq2      = (const float*)d_in[14];
    const float* bq2      = (const float*)d_in[15];
    const float* wk2      = (const float*)d_in[16];
    const float* bk2      = (const float*)d_in[17];
    const float* wv2      = (const float*)d_in[18];
    const float* bv2      = (const float*)d_in[19];
    const float* we2      = (const float*)d_in[20];
    const float* wskip2   = (const float*)d_in[21];
    const float* bskip2   = (const float*)d_in[22];
    const float* wc       = (const float*)d_in[23];
    const float* bc       = (const float*)d_in[24];

    const int N = in_sizes[0] / 128;
    const int E = in_sizes[2] / 32;
    const int* src = eidx;
    const int* dst = eidx + E;
    float* out = (float*)d_out;

    char* ws = (char*)d_ws;
    const size_t fbytes = (size_t)N * HC_DIM * sizeof(float);
    float* B0 = (float*)(ws + 0 * fbytes);
    float* B1 = (float*)(ws + 1 * fbytes);
    float* B2 = (float*)(ws + 2 * fbytes);
    float* B3 = (float*)(ws + 3 * fbytes);
    float* B4 = (float*)(ws + 4 * fbytes);
    char* p = ws + 5 * fbytes;
    float* S2   = (float*)p; p += (size_t)N * 32 * sizeof(float);
    float* WqP  = (float*)p; p += (size_t)256 * 256 * sizeof(float);
    float* bqP  = (float*)p; p += 256 * sizeof(float);
    int* rowptr = (int*)p;   p += (size_t)(N + 2) * sizeof(int);
    int* cursor = (int*)p;   p += (size_t)N * sizeof(int);
    int2* el2   = (int2*)p;  // 8B aligned (offsets above sum to multiple of 8)

    const dim3 b256(256);
    const dim3 gnode((N + 3) / 4);
    const dim3 ghg((N + 31) / 32);

    // CSR build
    hipMemsetAsync(cursor, 0, (size_t)N * sizeof(int), stream);
    count_kernel<<<dim3((E + 255) / 256), b256, 0, stream>>>(dst, E, cursor);
    scan_kernel<<<dim3(1), dim3(1024), 0, stream>>>(cursor, rowptr, N);
    scatter_kernel<<<dim3((E + 255) / 256), b256, 0, stream>>>(src, dst, E, cursor, el2);

    // ===== conv1 =====
    wfold_kernel<<<dim3((129 * 256 + 255) / 256), b256, 0, stream>>>(wq1, bq1, we1, WqP, bqP, 128);
    dim3 gg((N + 127) / 128, 2);
    gemm128<<<gg, b256, 0, stream>>>(x, wq1, bq1, B0, N, 256, 128);     // q
    gemm128<<<gg, b256, 0, stream>>>(x, wk1, bk1, B1, N, 256, 128);     // k
    gemm128<<<gg, b256, 0, stream>>>(x, wv1, bv1, B2, N, 256, 128);     // v
    gemm128<<<gg, b256, 0, stream>>>(x, wskip1, bskip1, B3, N, 256, 128); // skip1
    gemm128<<<gg, b256, 0, stream>>>(x, WqP, bqP, B4, N, 256, 128);     // P

    attn_kernel<<<gnode, b256, 0, stream>>>(B0, B4, B1, B2, eattr, el2, rowptr,
                                            B0 /*accV*/, B4 /*accA*/, N);
    headgemm_kernel<<<ghg, b256, 0, stream>>>(B0, B4, B3, we1, B1 /*Z*/, N);
    ln_kernel<<<gnode, b256, 0, stream>>>(B1, g1, b1, B2 /*h*/, N);

    // ===== conv2 =====
    wfold_kernel<<<dim3((257 * 256 + 255) / 256), b256, 0, stream>>>(wq2, bq2, we2, WqP, bqP, 256);
    gemm128<<<gg, b256, 0, stream>>>(B2, wq2, bq2, B0, N, 256, 256);    // q
    gemm128<<<gg, b256, 0, stream>>>(B2, wk2, bk2, B3, N, 256, 256);    // k
    gemm128<<<gg, b256, 0, stream>>>(B2, wv2, bv2, B4, N, 256, 256);    // v
    gemm128<<<gg, b256, 0, stream>>>(B2, WqP, bqP, B1, N, 256, 256);    // P
    gemm_bias<<<dim3((N + 63) / 64, 1), b256, 0, stream>>>(B2, wskip2, bskip2, S2, N, 32, 256);

    attn_kernel<<<gnode, b256, 0, stream>>>(B0, B1, B3, B4, eattr, el2, rowptr,
                                            B0 /*accV*/, B1 /*accA*/, N);
    headgemm_kernel<<<ghg, b256, 0, stream>>>(B0, B1, (const float*)nullptr, we2, B2 /*Z2*/, N);
    final_kernel<<<gnode, b256, 0, stream>>>(B2, S2, wc, bc, out, N);
}

// Round 7
// 1126.377 us; speedup vs baseline: 1.4956x; 1.2667x over previous
//
#include <hip/hip_runtime.h>
#include <math.h>

#define HC_DIM 256
#define E_DIM 32

typedef __attribute__((ext_vector_type(8))) short bf16x8;
typedef __attribute__((ext_vector_type(4))) float f32x4;

static __device__ __forceinline__ const float4& ldf4(const float* p) {
    return *reinterpret_cast<const float4*>(p);
}
static __device__ __forceinline__ ushort f2bf(float f) {
    union { float f; unsigned u; } x; x.f = f;
    unsigned u = x.u + 0x7FFF + ((x.u >> 16) & 1);
    return (ushort)(u >> 16);
}

// ---------------- CSR build ----------------
__global__ __launch_bounds__(256) void count_kernel(const int* __restrict__ dst, int E,
                                                    int* __restrict__ cnt) {
    int e = blockIdx.x * 256 + threadIdx.x;
    if (e < E) atomicAdd(&cnt[dst[e]], 1);
}

__global__ __launch_bounds__(1024) void scan_kernel(int* __restrict__ cnt,
                                                    int* __restrict__ rowptr, int n) {
    __shared__ int sm[1024];
    __shared__ int carry;
    if (threadIdx.x == 0) carry = 0;
    __syncthreads();
    for (int base = 0; base < n; base += 1024) {
        int i = base + (int)threadIdx.x;
        int val = (i < n) ? cnt[i] : 0;
        sm[threadIdx.x] = val;
        __syncthreads();
        for (int off = 1; off < 1024; off <<= 1) {
            int t = (threadIdx.x >= (unsigned)off) ? sm[threadIdx.x - off] : 0;
            __syncthreads();
            sm[threadIdx.x] += t;
            __syncthreads();
        }
        int incl = sm[threadIdx.x];
        int excl = carry + incl - val;
        if (i < n) { rowptr[i] = excl; cnt[i] = excl; }
        __syncthreads();
        if (threadIdx.x == 1023) carry += sm[1023];
        __syncthreads();
    }
    if (threadIdx.x == 0) rowptr[n] = carry;
}

__global__ __launch_bounds__(256) void scatter_kernel(const int* __restrict__ src,
                                                      const int* __restrict__ dst, int E,
                                                      int* __restrict__ cursor,
                                                      int2* __restrict__ el2) {
    int e = blockIdx.x * 256 + threadIdx.x;
    if (e < E) {
        int p = atomicAdd(&cursor[dst[e]], 1);
        el2[p] = make_int2(src[e], e);
    }
}

// ---------------- weight fold: WqP[r, h*32+d] = sum_c wq[r,h*32+c]*we[d,h*32+c] ----------------
__global__ __launch_bounds__(256) void wfold_kernel(const float* __restrict__ wq,
                                                    const float* __restrict__ bq,
                                                    const float* __restrict__ we,
                                                    float* __restrict__ WqP,
                                                    float* __restrict__ bqP, int K) {
    int t = blockIdx.x * 256 + threadIdx.x;
    if (t >= (K + 1) * 256) return;
    int r = t >> 8, col = t & 255;
    int h = col >> 5, d = col & 31;
    const float* srow = (r < K) ? (wq + (size_t)r * HC_DIM + h * 32) : (bq + h * 32);
    const float* wrow = we + (size_t)d * HC_DIM + h * 32;
    float s = 0.f;
#pragma unroll
    for (int c4 = 0; c4 < 8; ++c4) {
        float4 a = ldf4(srow + c4 * 4);
        float4 b = ldf4(wrow + c4 * 4);
        s += a.x * b.x + a.y * b.y + a.z * b.z + a.w * b.w;
    }
    if (r < K) WqP[(size_t)r * HC_DIM + col] = s;
    else bqP[col] = s;
}

// ---------------- weight pack (transpose + bf16): Wt[n][k] = W[k][n] ----------------
__global__ __launch_bounds__(256) void pack_w1(
    const float* __restrict__ wq, const float* __restrict__ bq,
    const float* __restrict__ wk, const float* __restrict__ bk,
    const float* __restrict__ wv, const float* __restrict__ bv,
    const float* __restrict__ wsk, const float* __restrict__ bsk,
    const float* __restrict__ wp, const float* __restrict__ bp,
    ushort* __restrict__ Wt, float* __restrict__ bias) {
    int t = blockIdx.x * 256 + threadIdx.x;
    if (t >= 1280 * 128) return;
    int n = t >> 7, k = t & 127;
    int s = n >> 8, nn = n & 255;
    const float* W[5] = {wq, wk, wv, wsk, wp};
    const float* B[5] = {bq, bk, bv, bsk, bp};
    Wt[t] = f2bf(W[s][(size_t)k * HC_DIM + nn]);
    if (k == 0) bias[n] = B[s][nn];
}

__global__ __launch_bounds__(256) void pack_w2(
    const float* __restrict__ wq, const float* __restrict__ bq,
    const float* __restrict__ wk, const float* __restrict__ bk,
    const float* __restrict__ wv, const float* __restrict__ bv,
    const float* __restrict__ wp, const float* __restrict__ bp,
    ushort* __restrict__ Wt, float* __restrict__ bias) {
    int t = blockIdx.x * 256 + threadIdx.x;
    if (t >= 1024 * 256) return;
    int n = t >> 8, k = t & 255;
    int s = n >> 8, nn = n & 255;
    const float* W[4] = {wq, wk, wv, wp};
    const float* B[4] = {bq, bk, bv, bp};
    Wt[t] = f2bf(W[s][(size_t)k * HC_DIM + nn]);
    if (k == 0) bias[n] = B[s][nn];
}

// ---------------- bf16 MFMA GEMM: Y = A[M,K]f32(->bf16) @ Wt[N,K]^T bf16 + bias ----------------
// 128x128 tile, BK=64, 4 waves (2x2), 64x64 per wave via 16x16x32 MFMA.
// A converted f32->bf16 during LDS staging (no bf16 activation buffer in ws).
struct OutPtrs { float* p[5]; };

__global__ __launch_bounds__(256) void gemm_mfma(
    const float* __restrict__ A, const ushort* __restrict__ Wt,
    const float* __restrict__ bias, OutPtrs outs, int M, int K) {
    __shared__ ushort As[128][72];   // row stride 144B
    __shared__ ushort Bs[128][72];
    const int tid = threadIdx.x;
    const int m0 = blockIdx.x * 128, n0 = blockIdx.y * 128;
    const int lane = tid & 63;
    const int w = tid >> 6;
    const int wm = w >> 1, wn = w & 1;
    const int lr = lane & 15;
    const int lk = (lane >> 4) * 8;      // k-offset within 32-wide MFMA step
    const int r = tid >> 1, hf = tid & 1; // staging: row, half(32 elems)
    const int rA = (m0 + r < M) ? (m0 + r) : (M - 1);

    f32x4 acc[4][4] = {};
    for (int kt = 0; kt < K; kt += 64) {
        const float* ga = A + (size_t)rA * K + kt + hf * 32;
        const ushort* gb = Wt + (size_t)(n0 + r) * K + kt + hf * 32;
        float4 fa[8];
        uint4 vb[4];
#pragma unroll
        for (int c = 0; c < 8; ++c) fa[c] = ldf4(ga + c * 4);
#pragma unroll
        for (int c = 0; c < 4; ++c) vb[c] = *reinterpret_cast<const uint4*>(gb + c * 8);
        __syncthreads();
#pragma unroll
        for (int c = 0; c < 4; ++c) {
            uint4 pa;
            pa.x = (unsigned)f2bf(fa[2 * c].x) | ((unsigned)f2bf(fa[2 * c].y) << 16);
            pa.y = (unsigned)f2bf(fa[2 * c].z) | ((unsigned)f2bf(fa[2 * c].w) << 16);
            pa.z = (unsigned)f2bf(fa[2 * c + 1].x) | ((unsigned)f2bf(fa[2 * c + 1].y) << 16);
            pa.w = (unsigned)f2bf(fa[2 * c + 1].z) | ((unsigned)f2bf(fa[2 * c + 1].w) << 16);
            *reinterpret_cast<uint4*>(&As[r][hf * 32 + c * 8]) = pa;
            *reinterpret_cast<uint4*>(&Bs[r][hf * 32 + c * 8]) = vb[c];
        }
        __syncthreads();
#pragma unroll
        for (int kk = 0; kk < 2; ++kk) {
            bf16x8 af[4], bfr[4];
#pragma unroll
            for (int i = 0; i < 4; ++i) {
                af[i]  = *reinterpret_cast<const bf16x8*>(&As[wm * 64 + i * 16 + lr][kk * 32 + lk]);
                bfr[i] = *reinterpret_cast<const bf16x8*>(&Bs[wn * 64 + i * 16 + lr][kk * 32 + lk]);
            }
#pragma unroll
            for (int mi = 0; mi < 4; ++mi)
#pragma unroll
                for (int ni = 0; ni < 4; ++ni)
                    acc[mi][ni] = __builtin_amdgcn_mfma_f32_16x16x32_bf16(
                        af[mi], bfr[ni], acc[mi][ni], 0, 0, 0);
        }
    }
    // store: D[row=(lane>>4)*4+j][col=lane&15] per 16x16 frag
#pragma unroll
    for (int ni = 0; ni < 4; ++ni) {
        const int cidx = n0 + wn * 64 + ni * 16;
        float* bp = outs.p[cidx >> 8];
        const int colo = (cidx & 255) + lr;
        const float bsv = bias[cidx + lr];
#pragma unroll
        for (int mi = 0; mi < 4; ++mi) {
#pragma unroll
            for (int j = 0; j < 4; ++j) {
                const int row = m0 + wm * 64 + mi * 16 + (lane >> 4) * 4 + j;
                if (row < M)
                    bp[(size_t)row * HC_DIM + colo] = acc[mi][ni][j] + bsv;
            }
        }
    }
}

// ---------------- small-N GEMM (N=32), f32 ----------------
__global__ __launch_bounds__(256) void gemm_bias(const float* __restrict__ A,
                                                 const float* __restrict__ W,
                                                 const float* __restrict__ bias,
                                                 float* __restrict__ Y,
                                                 int M, int N, int K) {
    __shared__ float As[16][68];
    __shared__ float Ws[16][68];
    const int tid = threadIdx.x;
    const int tx = tid & 15, ty = tid >> 4;
    const int m0 = blockIdx.x * 64, n0 = blockIdx.y * 64;
    const int lm = tid >> 2;
    const int lk = (tid & 3) << 2;
    const int wk = tid >> 4;
    const int wn = (tid & 15) << 2;
    float acc[4][4] = {{0.f}};
    for (int k0 = 0; k0 < K; k0 += 16) {
        float4 a = {0.f, 0.f, 0.f, 0.f};
        if (m0 + lm < M) a = ldf4(A + (size_t)(m0 + lm) * K + k0 + lk);
        As[lk + 0][lm] = a.x; As[lk + 1][lm] = a.y;
        As[lk + 2][lm] = a.z; As[lk + 3][lm] = a.w;
        float4 wv = {0.f, 0.f, 0.f, 0.f};
        if (n0 + wn < N) wv = ldf4(W + (size_t)(k0 + wk) * N + n0 + wn);
        *reinterpret_cast<float4*>(&Ws[wk][wn]) = wv;
        __syncthreads();
#pragma unroll
        for (int kk = 0; kk < 16; ++kk) {
            float4 av = *reinterpret_cast<const float4*>(&As[kk][ty << 2]);
            float4 bv = *reinterpret_cast<const float4*>(&Ws[kk][tx << 2]);
            float aa[4] = {av.x, av.y, av.z, av.w};
            float bb[4] = {bv.x, bv.y, bv.z, bv.w};
#pragma unroll
            for (int i = 0; i < 4; ++i)
#pragma unroll
                for (int j = 0; j < 4; ++j)
                    acc[i][j] = fmaf(aa[i], bb[j], acc[i][j]);
        }
        __syncthreads();
    }
    if (n0 + (tx << 2) < N) {
        float4 bb = ldf4(bias + n0 + (tx << 2));
#pragma unroll
        for (int i = 0; i < 4; ++i) {
            int m = m0 + (ty << 2) + i;
            if (m < M) {
                float4 o;
                o.x = acc[i][0] + bb.x; o.y = acc[i][1] + bb.y;
                o.z = acc[i][2] + bb.z; o.w = acc[i][3] + bb.w;
                *reinterpret_cast<float4*>(Y + (size_t)m * N + n0 + (tx << 2)) = o;
            }
        }
    }
}

// ---------------- edge-gather attention core: one wave per dst node ----------------
__global__ __launch_bounds__(256) void attn_kernel(
    const float* __restrict__ q, const float* __restrict__ Pm,
    const float* __restrict__ k, const float* __restrict__ v,
    const float* __restrict__ ea,
    const int2* __restrict__ el2, const int* __restrict__ rowptr,
    float* __restrict__ accV, float* __restrict__ accA, int nN) {
    const int wid = threadIdx.x >> 6, lane = threadIdx.x & 63;
    const int node = blockIdx.x * 4 + wid;
    if (node >= nN) return;
    const int hc0 = lane << 2;
    const int d0 = (lane & 7) << 2;

    const float4 qv = ldf4(q + (size_t)node * HC_DIM + hc0);
    const float4 Pv = ldf4(Pm + (size_t)node * HC_DIM + hc0);
    const float* kb = k + hc0;
    const float* vb = v + hc0;
    const float* ab = ea + d0;

    float m = -INFINITY, denom = 0.f;
    float ax = 0.f, ay = 0.f, az = 0.f, aw = 0.f;
    float A0 = 0.f, A1 = 0.f, A2 = 0.f, A3 = 0.f;
    const int e0 = rowptr[node], e1 = rowptr[node + 1];
    for (int cb = e0; cb < e1; cb += 64) {
        const int cnt = min(64, e1 - cb);
        const int2 ee = el2[cb + min(lane, cnt - 1)];
        for (int g = 0; g < cnt; g += 8) {
            float4 ku4[8], vu4[8], au4[8];
#pragma unroll
            for (int u = 0; u < 8; ++u) {
                const int jj = (g + u < cnt) ? (g + u) : (cnt - 1);
                const int s  = __shfl(ee.x, jj);
                const int e2 = __shfl(ee.y, jj);
                ku4[u] = ldf4(kb + (size_t)s * HC_DIM);
                vu4[u] = ldf4(vb + (size_t)s * HC_DIM);
                au4[u] = ldf4(ab + (size_t)e2 * E_DIM);
            }
            float lg[8];
#pragma unroll
            for (int u = 0; u < 8; ++u) {
                float lp = qv.x * ku4[u].x + qv.y * ku4[u].y +
                           qv.z * ku4[u].z + qv.w * ku4[u].w +
                           au4[u].x * Pv.x + au4[u].y * Pv.y +
                           au4[u].z * Pv.z + au4[u].w * Pv.w;
                lp += __shfl_xor(lp, 1); lp += __shfl_xor(lp, 2); lp += __shfl_xor(lp, 4);
                lg[u] = lp * 0.17677669529663687f;
            }
            float gm = lg[0];
#pragma unroll
            for (int u = 1; u < 8; ++u) gm = fmaxf(gm, lg[u]);
            float wu[8], gs = 0.f;
#pragma unroll
            for (int u = 0; u < 8; ++u) {
                wu[u] = (g + u < cnt) ? __expf(lg[u] - gm) : 0.f;
                gs += wu[u];
            }
            float gax = 0.f, gay = 0.f, gaz = 0.f, gaw = 0.f;
            float gA0 = 0.f, gA1 = 0.f, gA2 = 0.f, gA3 = 0.f;
#pragma unroll
            for (int u = 0; u < 8; ++u) {
                gax = fmaf(wu[u], vu4[u].x, gax);
                gay = fmaf(wu[u], vu4[u].y, gay);
                gaz = fmaf(wu[u], vu4[u].z, gaz);
                gaw = fmaf(wu[u], vu4[u].w, gaw);
                gA0 = fmaf(wu[u], au4[u].x, gA0);
                gA1 = fmaf(wu[u], au4[u].y, gA1);
                gA2 = fmaf(wu[u], au4[u].z, gA2);
                gA3 = fmaf(wu[u], au4[u].w, gA3);
            }
            const float mn = fmaxf(m, gm);
            const float sc = __expf(m - mn);
            const float gsc = __expf(gm - mn);
            denom = denom * sc + gs * gsc;
            ax = ax * sc + gax * gsc;
            ay = ay * sc + gay * gsc;
            az = az * sc + gaz * gsc;
            aw = aw * sc + gaw * gsc;
            A0 = A0 * sc + gA0 * gsc;
            A1 = A1 * sc + gA1 * gsc;
            A2 = A2 * sc + gA2 * gsc;
            A3 = A3 * sc + gA3 * gsc;
            m = mn;
        }
    }
    const float inv = 1.f / (denom + 1e-16f);
    float4 oV, oA;
    oV.x = ax * inv; oV.y = ay * inv; oV.z = az * inv; oV.w = aw * inv;
    oA.x = A0 * inv; oA.y = A1 * inv; oA.z = A2 * inv; oA.w = A3 * inv;
    *reinterpret_cast<float4*>(accV + (size_t)node * HC_DIM + hc0) = oV;
    *reinterpret_cast<float4*>(accA + (size_t)node * HC_DIM + hc0) = oA;
}

// ---------------- per-head epilogue GEMM: Z = accV + accA @ we (+skip) ----------------
__global__ __launch_bounds__(256) void headgemm_kernel(
    const float* __restrict__ accV, const float* __restrict__ accA,
    const float* __restrict__ skipb, const float* __restrict__ we,
    float* __restrict__ Z, int nN) {
    __shared__ float Al[32][256];
    const int tid = threadIdx.x;
    const int n0 = blockIdx.x * 32;
    const int c = tid;
    const int h = c >> 5;
    float wreg[32];
#pragma unroll
    for (int d = 0; d < 32; ++d) wreg[d] = we[(size_t)d * HC_DIM + c];
    const int rows = min(32, nN - n0);
#pragma unroll
    for (int i = 0; i < 8; ++i) {
        const int f4 = i * 256 + tid;
        const int r = f4 >> 6, c4 = (f4 & 63) << 2;
        float4 a = (r < rows) ? ldf4(accA + (size_t)(n0 + r) * HC_DIM + c4)
                              : make_float4(0.f, 0.f, 0.f, 0.f);
        *reinterpret_cast<float4*>(&Al[r][c4]) = a;
    }
    __syncthreads();
    for (int n = 0; n < rows; ++n) {
        const float* arow = &Al[n][h * 32];
        float s = 0.f;
#pragma unroll
        for (int d4 = 0; d4 < 8; ++d4) {
            const float4 a = *reinterpret_cast<const float4*>(arow + d4 * 4);
            s += a.x * wreg[d4 * 4 + 0] + a.y * wreg[d4 * 4 + 1] +
                 a.z * wreg[d4 * 4 + 2] + a.w * wreg[d4 * 4 + 3];
        }
        const size_t off = (size_t)(n0 + n) * HC_DIM + c;
        float z = accV[off] + s;
        if (skipb) z += skipb[off];
        Z[off] = z;
    }
}

// ---------------- conv1 epilogue: relu + LayerNorm (f32 out) ----------------
__global__ __launch_bounds__(256) void ln_kernel(
    const float* __restrict__ Z, const float* __restrict__ g,
    const float* __restrict__ b, float* __restrict__ hout, int nN) {
    const int wid = threadIdx.x >> 6, lane = threadIdx.x & 63;
    const int node = blockIdx.x * 4 + wid;
    if (node >= nN) return;
    const int hc0 = lane << 2;
    const float4 z = ldf4(Z + (size_t)node * HC_DIM + hc0);
    const float ox = fmaxf(z.x, 0.f), oy = fmaxf(z.y, 0.f);
    const float oz = fmaxf(z.z, 0.f), ow = fmaxf(z.w, 0.f);
    float s1 = ox + oy + oz + ow;
    float s2 = ox * ox + oy * oy + oz * oz + ow * ow;
#pragma unroll
    for (int msk = 1; msk < 64; msk <<= 1) {
        s1 += __shfl_xor(s1, msk);
        s2 += __shfl_xor(s2, msk);
    }
    const float mu = s1 * (1.f / 256.f);
    const float var = s2 * (1.f / 256.f) - mu * mu;
    const float rstd = rsqrtf(var + 1e-5f);
    const float4 gv = ldf4(g + hc0);
    const float4 bv = ldf4(b + hc0);
    float4 o;
    o.x = (ox - mu) * rstd * gv.x + bv.x;
    o.y = (oy - mu) * rstd * gv.y + bv.y;
    o.z = (oz - mu) * rstd * gv.z + bv.z;
    o.w = (ow - mu) * rstd * gv.w + bv.w;
    *reinterpret_cast<float4*>(hout + (size_t)node * HC_DIM + hc0) = o;
}

// ---------------- conv2 epilogue ----------------
__global__ __launch_bounds__(256) void final_kernel(
    const float* __restrict__ Z2, const float* __restrict__ skip2,
    const float* __restrict__ wc, const float* __restrict__ bc,
    float* __restrict__ out, int nN) {
    const int wid = threadIdx.x >> 6, lane = threadIdx.x & 63;
    const int node = blockIdx.x * 4 + wid;
    if (node >= nN) return;
    const int hc0 = lane << 2;
    const float4 z = ldf4(Z2 + (size_t)node * HC_DIM + hc0);
    float ox = z.x, oy = z.y, oz = z.z, ow = z.w;
#pragma unroll
    for (int msk = 8; msk < 64; msk <<= 1) {
        ox += __shfl_xor(ox, msk);
        oy += __shfl_xor(oy, msk);
        oz += __shfl_xor(oz, msk);
        ow += __shfl_xor(ow, msk);
    }
    const int c0 = (lane & 7) << 2;
    const float4 sk = ldf4(skip2 + (size_t)node * 32 + c0);
    const float yx = fmaxf(ox * 0.125f + sk.x, 0.f);
    const float yy = fmaxf(oy * 0.125f + sk.y, 0.f);
    const float yz = fmaxf(oz * 0.125f + sk.z, 0.f);
    const float yw = fmaxf(ow * 0.125f + sk.w, 0.f);
    float p0 = yx * wc[(c0 + 0) * 2 + 0] + yy * wc[(c0 + 1) * 2 + 0] +
               yz * wc[(c0 + 2) * 2 + 0] + yw * wc[(c0 + 3) * 2 + 0];
    float p1 = yx * wc[(c0 + 0) * 2 + 1] + yy * wc[(c0 + 1) * 2 + 1] +
               yz * wc[(c0 + 2) * 2 + 1] + yw * wc[(c0 + 3) * 2 + 1];
#pragma unroll
    for (int msk = 1; msk < 8; msk <<= 1) {
        p0 += __shfl_xor(p0, msk);
        p1 += __shfl_xor(p1, msk);
    }
    if (lane == 0) {
        out[(size_t)node * 2 + 0] = p0 + bc[0];
        out[(size_t)node * 2 + 1] = p1 + bc[1];
    }
}

extern "C" void kernel_launch(void* const* d_in, const int* in_sizes, int n_in,
                              void* d_out, int out_size, void* d_ws, size_t ws_size,
                              hipStream_t stream) {
    const float* x        = (const float*)d_in[0];
    const int*   eidx     = (const int*)d_in[1];
    const float* eattr    = (const float*)d_in[2];
    const float* wq1      = (const float*)d_in[3];
    const float* bq1      = (const float*)d_in[4];
    const float* wk1      = (const float*)d_in[5];
    const float* bk1      = (const float*)d_in[6];
    const float* wv1      = (const float*)d_in[7];
    const float* bv1      = (const float*)d_in[8];
    const float* we1      = (const float*)d_in[9];
    const float* wskip1   = (const float*)d_in[10];
    const float* bskip1   = (const float*)d_in[11];
    const float* g1       = (const float*)d_in[12];
    const float* b1       = (const float*)d_in[13];
    const float* wq2      = (const float*)d_in[14];
    const float* bq2      = (const float*)d_in[15];
    const float* wk2      = (const float*)d_in[16];
    const float* bk2      = (const float*)d_in[17];
    const float* wv2      = (const float*)d_in[18];
    const float* bv2      = (const float*)d_in[19];
    const float* we2      = (const float*)d_in[20];
    const float* wskip2   = (const float*)d_in[21];
    const float* bskip2   = (const float*)d_in[22];
    const float* wc       = (const float*)d_in[23];
    const float* bc       = (const float*)d_in[24];

    const int N = in_sizes[0] / 128;
    const int E = in_sizes[2] / 32;
    const int* src = eidx;
    const int* dst = eidx + E;
    float* out = (float*)d_out;

    char* ws = (char*)d_ws;
    const size_t fbytes = (size_t)N * HC_DIM * sizeof(float);
    float* B0 = (float*)(ws + 0 * fbytes);
    float* B1 = (float*)(ws + 1 * fbytes);
    float* B2 = (float*)(ws + 2 * fbytes);
    float* B3 = (float*)(ws + 3 * fbytes);
    float* B4 = (float*)(ws + 4 * fbytes);
    char* p = ws + 5 * fbytes;
    float* S2    = (float*)p;  p += (size_t)N * 32 * sizeof(float);
    float* WqP   = (float*)p;  p += (size_t)256 * 256 * sizeof(float);
    float* bqP   = (float*)p;  p += 256 * sizeof(float);
    ushort* Wt1b = (ushort*)p; p += (size_t)1280 * 128 * sizeof(ushort);
    float* bias1 = (float*)p;  p += 1280 * sizeof(float);
    ushort* Wt2b = (ushort*)p; p += (size_t)1024 * 256 * sizeof(ushort);
    float* bias2 = (float*)p;  p += 1024 * sizeof(float);
    int* rowptr  = (int*)p;    p += (size_t)(N + 2) * sizeof(int);
    int* cursor  = (int*)p;    p += (size_t)N * sizeof(int);
    int2* el2    = (int2*)p;   // 8B aligned; total ws use ~254.8 MiB

    const dim3 b256(256);
    const dim3 gnode((N + 3) / 4);
    const dim3 ghg((N + 31) / 32);
    const int mblocks = (N + 127) / 128;

    // CSR build
    hipMemsetAsync(cursor, 0, (size_t)N * sizeof(int), stream);
    count_kernel<<<dim3((E + 255) / 256), b256, 0, stream>>>(dst, E, cursor);
    scan_kernel<<<dim3(1), dim3(1024), 0, stream>>>(cursor, rowptr, N);
    scatter_kernel<<<dim3((E + 255) / 256), b256, 0, stream>>>(src, dst, E, cursor, el2);

    // weight prep (conv1)
    wfold_kernel<<<dim3((129 * 256 + 255) / 256), b256, 0, stream>>>(wq1, bq1, we1, WqP, bqP, 128);
    pack_w1<<<dim3((1280 * 128 + 255) / 256), b256, 0, stream>>>(
        wq1, bq1, wk1, bk1, wv1, bv1, wskip1, bskip1, WqP, bqP, Wt1b, bias1);

    // ===== conv1: fused q|k|v|skip|P GEMM (bf16 MFMA, f32-A staging) =====
    OutPtrs o1; o1.p[0] = B0; o1.p[1] = B1; o1.p[2] = B2; o1.p[3] = B3; o1.p[4] = B4;
    gemm_mfma<<<dim3(mblocks, 10), b256, 0, stream>>>(x, Wt1b, bias1, o1, N, 128);

    attn_kernel<<<gnode, b256, 0, stream>>>(B0, B4, B1, B2, eattr, el2, rowptr,
                                            B0 /*accV*/, B4 /*accA*/, N);
    headgemm_kernel<<<ghg, b256, 0, stream>>>(B0, B4, B3, we1, B1 /*Z*/, N);
    ln_kernel<<<gnode, b256, 0, stream>>>(B1, g1, b1, B3 /*h f32*/, N);

    // ===== conv2 =====
    wfold_kernel<<<dim3((257 * 256 + 255) / 256), b256, 0, stream>>>(wq2, bq2, we2, WqP, bqP, 256);
    pack_w2<<<dim3((1024 * 256 + 255) / 256), b256, 0, stream>>>(
        wq2, bq2, wk2, bk2, wv2, bv2, WqP, bqP, Wt2b, bias2);

    OutPtrs o2; o2.p[0] = B0; o2.p[1] = B1; o2.p[2] = B2; o2.p[3] = B4; o2.p[4] = B4;
    gemm_mfma<<<dim3(mblocks, 8), b256, 0, stream>>>(B3, Wt2b, bias2, o2, N, 256);
    gemm_bias<<<dim3((N + 63) / 64, 1), b256, 0, stream>>>(B3, wskip2, bskip2, S2, N, 32, 256);

    attn_kernel<<<gnode, b256, 0, stream>>>(B0, B4, B1, B2, eattr, el2, rowptr,
                                            B0 /*accV*/, B4 /*accA*/, N);
    headgemm_kernel<<<ghg, b256, 0, stream>>>(B0, B4, (const float*)nullptr, we2, B1 /*Z2*/, N);
    final_kernel<<<gnode, b256, 0, stream>>>(B1, S2, wc, bc, out, N);
}